// Round 11
// baseline (545.119 us; speedup 1.0000x reference)
//
#include <hip/hip_runtime.h>
#include <cstdint>
#include <cstddef>

#define B_GRAPHS 32
#define NPG      8192
#define N_NODES  (B_GRAPHS * NPG)   // 262144
#define DEG      8
#define NE       (N_NODES * DEG)    // 2097152
#define N1       32768              // B * 32*32  (grid 4)
#define N2       8192               // B * 16*16  (grid 8)
#define BKT_CAP  80
#define CPG      8                  // chunks per graph for parallel sorts

// ---------------------------------------------------------------------------
// Node-level precompute: a[i,o] = b[o] + sum_k h[i,k]*W[k,o] + px*W[IN,o] + py*W[IN+1,o]
// ---------------------------------------------------------------------------
template<int IN, int OUT>
__global__ __launch_bounds__(256)
void node_a_kernel(const float* __restrict__ h, const float* __restrict__ pos,
                   const float* __restrict__ W, const float* __restrict__ bias,
                   float* __restrict__ a, int n) {
    constexpr int FEAT = IN + 2;
    __shared__ float Ws[FEAT * OUT + OUT];
    for (int i = threadIdx.x; i < FEAT * OUT; i += 256) Ws[i] = W[i];
    for (int i = threadIdx.x; i < OUT; i += 256) Ws[FEAT * OUT + i] = bias[i];
    __syncthreads();
    int i = blockIdx.x * 256 + threadIdx.x;
    if (i >= n) return;

    float acc[OUT];
    #pragma unroll
    for (int o = 0; o < OUT; ++o) acc[o] = Ws[FEAT * OUT + o];

    float px = pos[i * 3 + 0], py = pos[i * 3 + 1];
    #pragma unroll
    for (int o = 0; o < OUT; ++o)
        acc[o] += px * Ws[IN * OUT + o] + py * Ws[(IN + 1) * OUT + o];

    if constexpr (IN % 4 == 0) {
        const float4* h4 = (const float4*)(h + (size_t)i * IN);
        for (int k4 = 0; k4 < IN / 4; ++k4) {
            float4 f = h4[k4];
            #pragma unroll
            for (int o = 0; o < OUT; ++o) {
                acc[o] += f.x * Ws[(k4 * 4 + 0) * OUT + o];
                acc[o] += f.y * Ws[(k4 * 4 + 1) * OUT + o];
                acc[o] += f.z * Ws[(k4 * 4 + 2) * OUT + o];
                acc[o] += f.w * Ws[(k4 * 4 + 3) * OUT + o];
            }
        }
    } else {
        for (int k = 0; k < IN; ++k) {
            float f = h[(size_t)i * IN + k];
            #pragma unroll
            for (int o = 0; o < OUT; ++o) acc[o] += f * Ws[k * OUT + o];
        }
    }
    float* ap = a + (size_t)i * OUT;
    #pragma unroll
    for (int o = 0; o < OUT; ++o) ap[o] = acc[o];
}

// ---------------------------------------------------------------------------
// Per-graph edge histogram (gcnt zeroed) + tiny serial scan.
// ---------------------------------------------------------------------------
__global__ __launch_bounds__(256)
void precount_kernel(const int* __restrict__ dst, int* __restrict__ gcnt) {
    __shared__ int hist[B_GRAPHS];
    if (threadIdx.x < B_GRAPHS) hist[threadIdx.x] = 0;
    __syncthreads();
    int gid = blockIdx.x * 256 + threadIdx.x;
    for (int e = gid; e < NE; e += 256 * 256)
        atomicAdd(&hist[dst[e] >> 13], 1);
    __syncthreads();
    if (threadIdx.x < B_GRAPHS) atomicAdd(&gcnt[threadIdx.x], hist[threadIdx.x]);
}

__global__ void gscan_kernel(const int* __restrict__ gcnt, int* __restrict__ gbase,
                             int* __restrict__ gcur) {
    if (threadIdx.x == 0) {
        int run = 0;
        for (int g = 0; g < B_GRAPHS; ++g) {
            gbase[g] = run; gcur[g] = run;
            run += gcnt[g];
        }
        gbase[B_GRAPHS] = run;
    }
}

// ---------------------------------------------------------------------------
// Bucket edges by graph, packed local (src<<13 | dst). Coalesced flushes.
// ---------------------------------------------------------------------------
__global__ __launch_bounds__(256)
void bucket_kernel(const int* __restrict__ src, const int* __restrict__ dst,
                   int* __restrict__ gcur, int* __restrict__ binned) {
    __shared__ int bins[B_GRAPHS][BKT_CAP];
    __shared__ int bcnt[B_GRAPHS], sbase[B_GRAPHS], sn[B_GRAPHS];
    int tid = threadIdx.x;
    if (tid < B_GRAPHS) bcnt[tid] = 0;
    __syncthreads();
    int wgbase = blockIdx.x * 2048;
    for (int sub = 0; sub < 2; ++sub) {
        int e0 = wgbase + sub * 1024 + tid * 4;
        int4 s4 = *(const int4*)&src[e0];
        int4 d4 = *(const int4*)&dst[e0];
        int ss[4] = {s4.x, s4.y, s4.z, s4.w};
        int dd[4] = {d4.x, d4.y, d4.z, d4.w};
        #pragma unroll
        for (int k = 0; k < 4; ++k) {
            int b = dd[k] >> 13;
            int pk = ((ss[k] & 8191) << 13) | (dd[k] & 8191);
            int pos = atomicAdd(&bcnt[b], 1);
            if (pos < BKT_CAP) bins[b][pos] = pk;
            else { int gp = atomicAdd(&gcur[b], 1); binned[gp] = pk; }
        }
        __syncthreads();
        if (tid < B_GRAPHS) {
            int nb = min(bcnt[tid], BKT_CAP);
            sn[tid] = nb;
            sbase[tid] = atomicAdd(&gcur[tid], nb);
        }
        __syncthreads();
        int b = tid >> 3, r = tid & 7;
        for (int k = r; k < sn[b]; k += 8) binned[sbase[b] + k] = bins[b][k];
        __syncthreads();
        if (tid < B_GRAPHS) bcnt[tid] = 0;
        __syncthreads();
    }
}

// ---------------------------------------------------------------------------
// Parallel chunked counting sort (hist -> global scan -> fill), 8 chunks/graph.
// ---------------------------------------------------------------------------
template<int BINS, int LEVB>
__global__ __launch_bounds__(1024)
void sort_hist_kernel(const int* __restrict__ binned, const int* __restrict__ gbase,
                      const int* __restrict__ gend, const int* __restrict__ c1,
                      int* __restrict__ H) {
    __shared__ int hist[BINS];
    int wg = blockIdx.x, g = wg >> 3, sub = wg & 7, t = threadIdx.x;
    for (int i = t; i < BINS; i += 1024) hist[i] = 0;
    __syncthreads();
    int segb = gbase[g], sege = gend[g];
    int csz = (sege - segb + CPG - 1) / CPG;
    int e0 = segb + sub * csz, e1 = min(e0 + csz, sege);
    int nodeb = g * NPG;
    for (int e = e0 + t; e < e1; e += 1024) {
        int pk = binned[e];
        if (LEVB) {
            int sc = c1[nodeb + (pk >> 13)];
            int dc = c1[nodeb + (pk & 8191)];
            if (sc != dc) atomicAdd(&hist[dc & (BINS - 1)], 1);
        } else {
            atomicAdd(&hist[(pk & 8191) >> 4], 1);
        }
    }
    __syncthreads();
    for (int b = t; b < BINS; b += 1024)
        H[(size_t)(g * BINS + b) * CPG + sub] = hist[b];
}

template<int BINS, int LEVB>
__global__ __launch_bounds__(1024)
void sort_fill_kernel(const int* __restrict__ binned, const int* __restrict__ gbase,
                      const int* __restrict__ gend, const int* __restrict__ c1,
                      const int* __restrict__ S, int* __restrict__ outv) {
    __shared__ int cur[BINS];
    int wg = blockIdx.x, g = wg >> 3, sub = wg & 7, t = threadIdx.x;
    for (int b = t; b < BINS; b += 1024)
        cur[b] = S[(size_t)(g * BINS + b) * CPG + sub];
    __syncthreads();
    int segb = gbase[g], sege = gend[g];
    int csz = (sege - segb + CPG - 1) / CPG;
    int e0 = segb + sub * csz, e1 = min(e0 + csz, sege);
    int nodeb = g * NPG;
    for (int e = e0 + t; e < e1; e += 1024) {
        int pk = binned[e];
        if (LEVB) {
            int sc = c1[nodeb + (pk >> 13)];
            int dc = c1[nodeb + (pk & 8191)];
            if (sc != dc) {
                int p = atomicAdd(&cur[dc & (BINS - 1)], 1);
                outv[p] = sc;
            }
        } else {
            int p = atomicAdd(&cur[(pk & 8191) >> 4], 1);
            outv[p] = pk;
        }
    }
}

// ---------------------------------------------------------------------------
// Hierarchical exclusive scan (n % 1024 == 0, nb up to ~2048).
// ---------------------------------------------------------------------------
__global__ __launch_bounds__(256)
void scan_reduce_kernel(const int* __restrict__ counts, int* __restrict__ blocksums) {
    int t = threadIdx.x;
    int4 v = *(const int4*)&counts[blockIdx.x * 1024 + t * 4];
    int s = v.x + v.y + v.z + v.w;
    #pragma unroll
    for (int off = 32; off > 0; off >>= 1) s += __shfl_xor(s, off, 64);
    __shared__ int ws[4];
    if ((t & 63) == 0) ws[t >> 6] = s;
    __syncthreads();
    if (t == 0) blocksums[blockIdx.x] = ws[0] + ws[1] + ws[2] + ws[3];
}

__global__ __launch_bounds__(256)
void scan_blocks_kernel(const int* __restrict__ blocksums, int* __restrict__ blockpref,
                        int* __restrict__ offsets, int nb, int n) {
    __shared__ int sh[256];
    int t = threadIdx.x;
    int C = (nb + 255) / 256;
    int base = t * C;
    int s = 0;
    for (int i = 0; i < C; ++i) { int idx = base + i; if (idx < nb) s += blocksums[idx]; }
    sh[t] = s;
    __syncthreads();
    #pragma unroll
    for (int d = 1; d < 256; d <<= 1) {
        int u = (t >= d) ? sh[t - d] : 0;
        __syncthreads();
        sh[t] += u;
        __syncthreads();
    }
    int run = sh[t] - s;
    for (int i = 0; i < C; ++i) {
        int idx = base + i;
        if (idx < nb) { int v = blocksums[idx]; blockpref[idx] = run; run += v; }
    }
    if (t == 255) offsets[n] = sh[255];
}

__global__ __launch_bounds__(256)
void scan_write_kernel(const int* __restrict__ counts, const int* __restrict__ blockpref,
                       int* __restrict__ offsets, int* __restrict__ cursor) {
    int b = blockIdx.x, t = threadIdx.x;
    int base = b * 1024 + t * 4;
    int4 v = *(const int4*)&counts[base];
    int s = v.x + v.y + v.z + v.w;
    __shared__ int sh[256];
    sh[t] = s;
    __syncthreads();
    #pragma unroll
    for (int d = 1; d < 256; d <<= 1) {
        int u = (t >= d) ? sh[t - d] : 0;
        __syncthreads();
        sh[t] += u;
        __syncthreads();
    }
    int pref = blockpref[b] + sh[t] - s;
    int4 o;
    o.x = pref;
    o.y = pref + v.x;
    o.z = o.y + v.y;
    o.w = o.z + v.z;
    *(int4*)&offsets[base] = o;
    if (cursor) *(int4*)&cursor[base] = o;
}

// ---------------------------------------------------------------------------
// Level-A fused conv1+pool1: one wg per 16-dst bucket; per-(dst,ch) LDS
// atomicMax slots with order-preserving uint keys. 512 threads = 32 edge
// streams x 16 ch (block-per-bucket amortizes per-wave overhead; round-10's
// wave-per-node was issue-overhead-bound at 91us vs 53us for this shape).
// ---------------------------------------------------------------------------
__global__ __launch_bounds__(512)
void gatherA_kernel(const float* __restrict__ a, const float* __restrict__ pos,
                    const float* __restrict__ Wp, const int* __restrict__ S,
                    const int* __restrict__ sortedA, const int* __restrict__ c1,
                    float* __restrict__ hp1) {
    __shared__ unsigned slot[256];
    int bid = blockIdx.x;
    int v = (bid & 7) * (B_GRAPHS * 512 / 8) + (bid >> 3);   // XCD-contiguous graphs
    int g = v >> 9;
    int t = threadIdx.x;
    if (t < 256) slot[t] = 0u;
    __syncthreads();
    int start = S[(size_t)v * CPG], end = S[(size_t)(v + 1) * CPG];
    int nodeb = g * NPG;
    int ch = t & 15, el = t >> 4;        // 32 edge streams
    for (int j = start + el; j < end; j += 32) {
        int pk = sortedA[j];
        float val = a[(size_t)(nodeb + (pk >> 13)) * 16 + ch];
        unsigned u = __float_as_uint(val);
        unsigned key = (u & 0x80000000u) ? ~u : (u | 0x80000000u);
        atomicMax(&slot[((pk & 15) << 4) + ch], key);
    }
    __syncthreads();
    if (t < 256) {
        int dl = t >> 4;
        unsigned k = slot[(dl << 4) + ch];
        if (k) {
            unsigned u = (k & 0x80000000u) ? (k ^ 0x80000000u) : ~k;
            float m = __uint_as_float(u);
            int dst = nodeb + ((v & 511) << 4) + dl;
            float px = pos[dst * 3 + 0], py = pos[dst * 3 + 1];
            float val = fmaxf(m - (px * Wp[ch] + py * Wp[16 + ch]), 0.0f);
            if (val > 0.0f)
                atomicMax((int*)&hp1[(size_t)c1[dst] * 16 + ch], __float_as_int(val));
        }
    }
}

// ---------------------------------------------------------------------------
// Level-C dedupe bitmap (parallel): LDS bitmap per chunk, merge via atomicOr.
// ---------------------------------------------------------------------------
__global__ __launch_bounds__(1024)
void bitC_kernel(const int* __restrict__ binned, const int* __restrict__ gbase,
                 const int* __restrict__ gend, const int* __restrict__ c12,
                 unsigned* __restrict__ bitsG) {
    __shared__ unsigned bits[2048];
    int wg = blockIdx.x, g = wg >> 3, sub = wg & 7, t = threadIdx.x;
    for (int i = t; i < 2048; i += 1024) bits[i] = 0;
    __syncthreads();
    int segb = gbase[g], sege = gend[g];
    int csz = (sege - segb + CPG - 1) / CPG;
    int e0 = segb + sub * csz, e1 = min(e0 + csz, sege);
    int nodeb = g * NPG, clb = g * 256;
    for (int e = e0 + t; e < e1; e += 1024) {
        int pk = binned[e];
        int sc = c12[nodeb + (pk >> 13)] - clb;
        int dc = c12[nodeb + (pk & 8191)] - clb;
        if (sc != dc) atomicOr(&bits[(dc << 3) + (sc >> 5)], 1u << (sc & 31));
    }
    __syncthreads();
    for (int i = t; i < 2048; i += 1024) {
        unsigned wv = bits[i];
        if (wv) atomicOr(&bitsG[((size_t)g << 11) + i], wv);
    }
}

__global__ __launch_bounds__(256)
void popcC_kernel(const unsigned* __restrict__ bitsG, int* __restrict__ pc) {
    int i = blockIdx.x * 256 + threadIdx.x;
    int s = 0;
    #pragma unroll
    for (int k = 0; k < 8; ++k) s += __popc(bitsG[((size_t)i << 3) + k]);
    pc[i] = s;
}

__global__ __launch_bounds__(256)
void emitC_kernel(const unsigned* __restrict__ bitsG, const int* __restrict__ SC,
                  int* __restrict__ csrC) {
    int i = blockIdx.x * 256 + threadIdx.x;
    int clb = (i >> 8) << 8;
    int p = SC[i];
    #pragma unroll
    for (int w = 0; w < 8; ++w) {
        unsigned word = bitsG[((size_t)i << 3) + w];
        while (word) {
            int b = __ffs(word) - 1;
            word &= word - 1;
            csrC[p++] = clb + (w << 5) + b;
        }
    }
}

// ---------------------------------------------------------------------------
// Coarse gather-max conv (wave per node, FPL floats/lane, XCD-swizzled).
// MODE 0: float4 stores by ch-group lanes.
// MODE 1: WAVE-LOCAL LDS transpose (no block barrier) -> channel-per-lane
//         coalesced atomicMax (consecutive lanes, consecutive 4B).
// ---------------------------------------------------------------------------
template<int OUT, int MODE, int STRIDE, int FPL>
__global__ __launch_bounds__(512)
void gatherR_kernel(const float* __restrict__ a, const float* __restrict__ pos,
                    const float* __restrict__ Wp, const int* __restrict__ S,
                    const int* __restrict__ csr, const int* __restrict__ outmap,
                    float* __restrict__ out, int nblocks) {
    constexpr int CH = OUT / FPL;         // ch-group lanes per edge
    constexpr int ES = 64 / CH;           // edge streams per wave
    constexpr int NV = FPL / 4;           // float4s per lane
    int bid = blockIdx.x;
    int sb = (bid & 7) * (nblocks >> 3) + (bid >> 3);   // XCD-contiguous ranges
    int v = sb * 8 + (threadIdx.x >> 6);
    int lane = threadIdx.x & 63;
    int ch = lane % CH, s = lane / CH;
    int l = S[(size_t)v * STRIDE], h = S[(size_t)(v + 1) * STRIDE];
    float4 m[NV];
    #pragma unroll
    for (int q = 0; q < NV; ++q) m[q] = make_float4(-1e30f, -1e30f, -1e30f, -1e30f);
    for (int j = l + s; j < h; j += ES) {
        int sc = csr[j];
        const float4* ap = (const float4*)&a[(size_t)sc * OUT + ch * FPL];
        #pragma unroll
        for (int q = 0; q < NV; ++q) {
            float4 f = ap[q];
            m[q].x = fmaxf(m[q].x, f.x); m[q].y = fmaxf(m[q].y, f.y);
            m[q].z = fmaxf(m[q].z, f.z); m[q].w = fmaxf(m[q].w, f.w);
        }
    }
    #pragma unroll
    for (int st = CH; st < 64; st <<= 1) {
        #pragma unroll
        for (int q = 0; q < NV; ++q) {
            m[q].x = fmaxf(m[q].x, __shfl_xor(m[q].x, st, 64));
            m[q].y = fmaxf(m[q].y, __shfl_xor(m[q].y, st, 64));
            m[q].z = fmaxf(m[q].z, __shfl_xor(m[q].z, st, 64));
            m[q].w = fmaxf(m[q].w, __shfl_xor(m[q].w, st, 64));
        }
    }
    if (MODE == 0) {
        if (s == 0) {
            float px = pos[v * 3 + 0], py = pos[v * 3 + 1];
            bool ne = h > l;
            #pragma unroll
            for (int q = 0; q < NV; ++q) {
                float4 wx = *(const float4*)&Wp[ch * FPL + q * 4];
                float4 wy = *(const float4*)&Wp[OUT + ch * FPL + q * 4];
                float4 val;
                val.x = ne ? fmaxf(m[q].x - (px * wx.x + py * wy.x), 0.0f) : 0.0f;
                val.y = ne ? fmaxf(m[q].y - (px * wx.y + py * wy.y), 0.0f) : 0.0f;
                val.z = ne ? fmaxf(m[q].z - (px * wx.z + py * wy.z), 0.0f) : 0.0f;
                val.w = ne ? fmaxf(m[q].w - (px * wx.w + py * wy.w), 0.0f) : 0.0f;
                *(float4*)&out[(size_t)v * OUT + ch * FPL + q * 4] = val;
            }
        }
    } else {
        // wave-local LDS transpose (written & read by the same wave: no barrier)
        __shared__ float red[8][OUT];
        int wid = threadIdx.x >> 6;
        if (s == 0) {
            #pragma unroll
            for (int q = 0; q < NV; ++q)
                *(float4*)&red[wid][ch * FPL + q * 4] = m[q];
        }
        if (lane < OUT) {
            float px = pos[v * 3 + 0], py = pos[v * 3 + 1];
            float val = red[wid][lane];
            float ct = px * Wp[lane] + py * Wp[OUT + lane];
            val = (h > l) ? fmaxf(val - ct, 0.0f) : 0.0f;
            if (val > 0.0f)
                atomicMax((int*)&out[(size_t)outmap[v] * OUT + lane], __float_as_int(val));
        }
    }
}

// ---------------------------------------------------------------------------
// Voxel cluster id + pos mean accumulation; finalize; out-cells; c12 compose.
// ---------------------------------------------------------------------------
__global__ __launch_bounds__(256)
void cluster_kernel(const float* __restrict__ pos, int* __restrict__ cluster,
                    float* __restrict__ psum, int* __restrict__ cnt,
                    int n, int batch_shift, float inv_grid, int cells) {
    int i = blockIdx.x * 256 + threadIdx.x;
    if (i >= n) return;
    float px = pos[i * 3 + 0], py = pos[i * 3 + 1], pz = pos[i * 3 + 2];
    int ix = min(max((int)floorf(px * inv_grid), 0), cells - 1);
    int iy = min(max((int)floorf(py * inv_grid), 0), cells - 1);
    int c = (i >> batch_shift) * cells * cells + iy * cells + ix;
    cluster[i] = c;
    atomicAdd(&psum[c * 3 + 0], px);
    atomicAdd(&psum[c * 3 + 1], py);
    atomicAdd(&psum[c * 3 + 2], pz);
    atomicAdd(&cnt[c], 1);
}

__global__ __launch_bounds__(256)
void posfin_kernel(const float* __restrict__ pos_sum, const int* __restrict__ cnt,
                   float* __restrict__ pos_new, int n_new) {
    int i = blockIdx.x * 256 + threadIdx.x;
    if (i >= n_new) return;
    float c = fmaxf((float)cnt[i], 1.0f);
    pos_new[i * 3 + 0] = pos_sum[i * 3 + 0] / c;
    pos_new[i * 3 + 1] = pos_sum[i * 3 + 1] / c;
    pos_new[i * 3 + 2] = pos_sum[i * 3 + 2] / c;
}

__global__ __launch_bounds__(256)
void cellout_kernel(const float* __restrict__ pos, int* __restrict__ cell, int n) {
    int i = blockIdx.x * 256 + threadIdx.x;
    if (i >= n) return;
    float px = pos[i * 3 + 0], py = pos[i * 3 + 1];
    int ix = min(max((int)floorf(px * (1.0f / 16.0f)), 0), 7);
    int iy = min(max((int)floorf(py * (1.0f / 16.0f)), 0), 7);
    cell[i] = (i >> 8) * 64 + iy * 8 + ix;
}

__global__ __launch_bounds__(256)
void c12map_kernel(const int* __restrict__ c1, const int* __restrict__ c2,
                   int* __restrict__ c12) {
    int i = blockIdx.x * 256 + threadIdx.x;
    if (i < N_NODES) c12[i] = c2[c1[i]];
}

// ---------------------------------------------------------------------------
// MLP head. mlp1: block = (k-chunk, col-chunk); thread owns one output col,
// accumulates ALL 32 batches in registers. g reads are wave-uniform -> scalar
// loads; Wl1 read exactly once chip-wide (16 MB).
// ---------------------------------------------------------------------------
__global__ __launch_bounds__(256)
void mlp1_kernel(const float* __restrict__ g, const float* __restrict__ Wl1,
                 float* __restrict__ hid) {
    int kc = blockIdx.x, oc = blockIdx.y, t = threadIdx.x;
    int col = oc * 256 + t;
    int kbase = kc * 128;
    float acc[32];
    #pragma unroll
    for (int b = 0; b < 32; ++b) acc[b] = 0.0f;
    #pragma unroll 4
    for (int j = 0; j < 128; ++j) {
        float w = Wl1[(size_t)(kbase + j) * 1024 + col];
        #pragma unroll
        for (int b = 0; b < 32; ++b)
            acc[b] += g[b * 4096 + kbase + j] * w;
    }
    #pragma unroll
    for (int b = 0; b < 32; ++b)
        atomicAdd(&hid[b * 1024 + col], acc[b]);
}

__global__ __launch_bounds__(64)
void mlp2_kernel(const float* __restrict__ hid, const float* __restrict__ bl1,
                 const float* __restrict__ Wl2, const float* __restrict__ bl2,
                 float* __restrict__ out) {
    int b = blockIdx.x, l = threadIdx.x;
    float hv[16];
    #pragma unroll
    for (int i = 0; i < 16; ++i) {
        int idx = l + i * 64;
        hv[i] = fmaxf(hid[(size_t)b * 1024 + idx] + bl1[idx], 0.0f);
    }
    float logits[10];
    #pragma unroll
    for (int c = 0; c < 10; ++c) {
        float p = 0.0f;
        #pragma unroll
        for (int i = 0; i < 16; ++i)
            p += hv[i] * Wl2[(size_t)(l + i * 64) * 10 + c];
        #pragma unroll
        for (int off = 32; off > 0; off >>= 1) p += __shfl_xor(p, off, 64);
        logits[c] = p + bl2[c];
    }
    float m = logits[0];
    #pragma unroll
    for (int c = 1; c < 10; ++c) m = fmaxf(m, logits[c]);
    float ssum = 0.0f;
    #pragma unroll
    for (int c = 0; c < 10; ++c) ssum += expf(logits[c] - m);
    float lse = logf(ssum);
    if (l < 10) out[b * 10 + l] = logits[l] - m - lse;
}

// ---------------------------------------------------------------------------
extern "C" void kernel_launch(void* const* d_in, const int* in_sizes, int n_in,
                              void* d_out, int out_size, void* d_ws, size_t ws_size,
                              hipStream_t stream) {
    const float* x    = (const float*)d_in[0];
    const float* pos0 = (const float*)d_in[1];
    const int*   ei   = (const int*)d_in[2];
    const float* W1 = (const float*)d_in[4];  const float* b1 = (const float*)d_in[5];
    const float* W2 = (const float*)d_in[6];  const float* b2 = (const float*)d_in[7];
    const float* W3 = (const float*)d_in[8];  const float* b3 = (const float*)d_in[9];
    const float* W4 = (const float*)d_in[10]; const float* b4 = (const float*)d_in[11];
    const float* W5 = (const float*)d_in[12]; const float* b5 = (const float*)d_in[13];
    const float* Wl1 = (const float*)d_in[14]; const float* bl1 = (const float*)d_in[15];
    const float* Wl2 = (const float*)d_in[16]; const float* bl2 = (const float*)d_in[17];
    const int* src0 = ei;
    const int* dst0 = ei + NE;
    float* out = (float*)d_out;

    float* w = (float*)d_ws;
    size_t off = 0;
    auto alloc = [&](size_t n) { float* p = w + off; off += (n + 3) & ~(size_t)3; return p; };

    // --- zero-init region (one memset) ---
    int*      gcnt  = (int*)alloc(32);
    unsigned* bitsG = (unsigned*)alloc(B_GRAPHS * 2048);
    float* hp1   = alloc((size_t)N1 * 16);
    float* psum1 = alloc((size_t)N1 * 3);
    int*   icnt1 = (int*)alloc(N1);
    float* hp2   = alloc((size_t)N2 * 32);
    float* psum2 = alloc((size_t)N2 * 3);
    int*   icnt2 = (int*)alloc(N2);
    float* g     = alloc((size_t)B_GRAPHS * 4096);
    float* hid   = alloc((size_t)B_GRAPHS * 1024);
    size_t zero_bytes = off * sizeof(float);
    // --- abuf (a at every level) ---
    float* abuf = alloc((size_t)N_NODES * 16);
    // --- union 1: binned (dead after bitC) -> h2, h4 ---
    float* ubase = alloc((size_t)NE);
    int*   binned = (int*)ubase;
    float* h2 = ubase;
    float* h4 = h2 + (size_t)N1 * 32;
    // --- union 2: sortedA (dead after gatherA) -> csrC (written by emitC) ---
    int* sortedA = (int*)alloc(NE);
    int* csrC = sortedA;
    // --- rest ---
    int* csrB = (int*)alloc(NE);
    int* H   = (int*)alloc((size_t)B_GRAPHS * 1024 * CPG + 4);
    int* S_A = (int*)alloc((size_t)B_GRAPHS * 512 * CPG + 4);
    int* S_B = (int*)alloc((size_t)B_GRAPHS * 1024 * CPG + 4);
    int* pc  = (int*)alloc(N2);
    int* SC  = (int*)alloc(N2 + 4);
    float* pos1 = alloc((size_t)N1 * 3);
    float* pos2 = alloc((size_t)N2 * 3);
    int* cell = (int*)alloc(N2);
    int* c1   = (int*)alloc(N_NODES);
    int* c2   = (int*)alloc(N1);
    int* c12  = (int*)alloc(N_NODES);
    int* gbase = (int*)alloc(64);
    int* gcur  = (int*)alloc(64);
    int* blocksums = (int*)alloc(2560);
    int* blockpref = (int*)alloc(2560);
    (void)ws_size; (void)in_sizes; (void)n_in; (void)out_size;

    hipMemsetAsync(d_ws, 0, zero_bytes, stream);

    auto hscan = [&](const int* cnts, int* offs, int n) {
        scan_reduce_kernel<<<n / 1024, 256, 0, stream>>>(cnts, blocksums);
        scan_blocks_kernel<<<1, 256, 0, stream>>>(blocksums, blockpref, offs, n / 1024, n);
        scan_write_kernel<<<n / 1024, 256, 0, stream>>>(cnts, blockpref, offs, nullptr);
    };

    // ===== level A: bucket by graph, bucket-16 sort, fused conv1+pool1 =====
    node_a_kernel<1, 16><<<N_NODES / 256, 256, 0, stream>>>(x, pos0, W1, b1, abuf, N_NODES);
    precount_kernel<<<256, 256, 0, stream>>>(dst0, gcnt);
    gscan_kernel<<<1, 64, 0, stream>>>(gcnt, gbase, gcur);
    bucket_kernel<<<NE / 2048, 256, 0, stream>>>(src0, dst0, gcur, binned);
    sort_hist_kernel<512, 0><<<B_GRAPHS * CPG, 1024, 0, stream>>>(binned, gbase, gcur, nullptr, H);
    hscan(H, S_A, B_GRAPHS * 512 * CPG);
    sort_fill_kernel<512, 0><<<B_GRAPHS * CPG, 1024, 0, stream>>>(binned, gbase, gcur, nullptr, S_A, sortedA);
    cluster_kernel<<<N_NODES / 256, 256, 0, stream>>>(pos0, c1, psum1, icnt1, N_NODES, 13, 0.25f, 32);
    gatherA_kernel<<<B_GRAPHS * 512, 512, 0, stream>>>(abuf, pos0, W1 + 16, S_A, sortedA, c1, hp1);
    posfin_kernel<<<N1 / 256, 256, 0, stream>>>(psum1, icnt1, pos1, N1);

    // ===== cluster maps =====
    cluster_kernel<<<N1 / 256, 256, 0, stream>>>(pos1, c2, psum2, icnt2, N1, 10, 0.125f, 16);
    posfin_kernel<<<N2 / 256, 256, 0, stream>>>(psum2, icnt2, pos2, N2);
    c12map_kernel<<<N_NODES / 256, 256, 0, stream>>>(c1, c2, c12);

    // ===== level-B CSR (1024-bin counting sort) =====
    sort_hist_kernel<1024, 1><<<B_GRAPHS * CPG, 1024, 0, stream>>>(binned, gbase, gcur, c1, H);
    hscan(H, S_B, B_GRAPHS * 1024 * CPG);
    sort_fill_kernel<1024, 1><<<B_GRAPHS * CPG, 1024, 0, stream>>>(binned, gbase, gcur, c1, S_B, csrB);

    // ===== level-C CSR (parallel bitmap dedupe; csrC aliases dead sortedA) =====
    bitC_kernel<<<B_GRAPHS * CPG, 1024, 0, stream>>>(binned, gbase, gcur, c12, bitsG);
    popcC_kernel<<<N2 / 256, 256, 0, stream>>>(bitsG, pc);
    hscan(pc, SC, N2);
    emitC_kernel<<<N2 / 256, 256, 0, stream>>>(bitsG, SC, csrC);

    // ===== level B: conv2 (store), conv3 (fused pool2) =====
    node_a_kernel<16, 32><<<N1 / 256, 256, 0, stream>>>(hp1, pos1, W2, b2, abuf, N1);
    gatherR_kernel<32, 0, CPG, 8><<<N1 / 8, 512, 0, stream>>>(abuf, pos1, W2 + 512, S_B, csrB, nullptr, h2, N1 / 8);
    node_a_kernel<32, 32><<<N1 / 256, 256, 0, stream>>>(h2, pos1, W3, b3, abuf, N1);
    gatherR_kernel<32, 1, CPG, 8><<<N1 / 8, 512, 0, stream>>>(abuf, pos1, W3 + 1024, S_B, csrB, c2, hp2, N1 / 8);

    // ===== level C: conv4 (store), conv5 (fused pool_out) =====
    node_a_kernel<32, 64><<<N2 / 256, 256, 0, stream>>>(hp2, pos2, W4, b4, abuf, N2);
    gatherR_kernel<64, 0, 1, 16><<<N2 / 8, 512, 0, stream>>>(abuf, pos2, W4 + 2048, SC, csrC, nullptr, h4, N2 / 8);
    node_a_kernel<64, 64><<<N2 / 256, 256, 0, stream>>>(h4, pos2, W5, b5, abuf, N2);
    cellout_kernel<<<N2 / 256, 256, 0, stream>>>(pos2, cell, N2);
    gatherR_kernel<64, 1, 1, 16><<<N2 / 8, 512, 0, stream>>>(abuf, pos2, W5 + 4096, SC, csrC, cell, g, N2 / 8);

    // ===== MLP head =====
    mlp1_kernel<<<dim3(32, 4), 256, 0, stream>>>(g, Wl1, hid);
    mlp2_kernel<<<32, 64, 0, stream>>>(hid, bl1, Wl2, bl2, out);
}

// Round 12
// 492.974 us; speedup vs baseline: 1.1058x; 1.1058x over previous
//
#include <hip/hip_runtime.h>
#include <cstdint>
#include <cstddef>

#define B_GRAPHS 32
#define NPG      8192
#define N_NODES  (B_GRAPHS * NPG)   // 262144
#define DEG      8
#define NE       (N_NODES * DEG)    // 2097152
#define N1       32768              // B * 32*32  (grid 4)
#define N2       8192               // B * 16*16  (grid 8)
#define BKT_CAP  80
#define CPG      8                  // chunks per graph for parallel sorts

// ---------------------------------------------------------------------------
// Node-level precompute: a[i,o] = b[o] + sum_k h[i,k]*W[k,o] + px*W[IN,o] + py*W[IN+1,o]
// ---------------------------------------------------------------------------
template<int IN, int OUT>
__global__ __launch_bounds__(256)
void node_a_kernel(const float* __restrict__ h, const float* __restrict__ pos,
                   const float* __restrict__ W, const float* __restrict__ bias,
                   float* __restrict__ a, int n) {
    constexpr int FEAT = IN + 2;
    __shared__ float Ws[FEAT * OUT + OUT];
    for (int i = threadIdx.x; i < FEAT * OUT; i += 256) Ws[i] = W[i];
    for (int i = threadIdx.x; i < OUT; i += 256) Ws[FEAT * OUT + i] = bias[i];
    __syncthreads();
    int i = blockIdx.x * 256 + threadIdx.x;
    if (i >= n) return;

    float acc[OUT];
    #pragma unroll
    for (int o = 0; o < OUT; ++o) acc[o] = Ws[FEAT * OUT + o];

    float px = pos[i * 3 + 0], py = pos[i * 3 + 1];
    #pragma unroll
    for (int o = 0; o < OUT; ++o)
        acc[o] += px * Ws[IN * OUT + o] + py * Ws[(IN + 1) * OUT + o];

    if constexpr (IN % 4 == 0) {
        const float4* h4 = (const float4*)(h + (size_t)i * IN);
        for (int k4 = 0; k4 < IN / 4; ++k4) {
            float4 f = h4[k4];
            #pragma unroll
            for (int o = 0; o < OUT; ++o) {
                acc[o] += f.x * Ws[(k4 * 4 + 0) * OUT + o];
                acc[o] += f.y * Ws[(k4 * 4 + 1) * OUT + o];
                acc[o] += f.z * Ws[(k4 * 4 + 2) * OUT + o];
                acc[o] += f.w * Ws[(k4 * 4 + 3) * OUT + o];
            }
        }
    } else {
        for (int k = 0; k < IN; ++k) {
            float f = h[(size_t)i * IN + k];
            #pragma unroll
            for (int o = 0; o < OUT; ++o) acc[o] += f * Ws[k * OUT + o];
        }
    }
    float* ap = a + (size_t)i * OUT;
    #pragma unroll
    for (int o = 0; o < OUT; ++o) ap[o] = acc[o];
}

// ---------------------------------------------------------------------------
// Per-graph edge histogram (gcnt zeroed) + tiny serial scan.
// ---------------------------------------------------------------------------
__global__ __launch_bounds__(256)
void precount_kernel(const int* __restrict__ dst, int* __restrict__ gcnt) {
    __shared__ int hist[B_GRAPHS];
    if (threadIdx.x < B_GRAPHS) hist[threadIdx.x] = 0;
    __syncthreads();
    int gid = blockIdx.x * 256 + threadIdx.x;
    for (int e = gid; e < NE; e += 256 * 256)
        atomicAdd(&hist[dst[e] >> 13], 1);
    __syncthreads();
    if (threadIdx.x < B_GRAPHS) atomicAdd(&gcnt[threadIdx.x], hist[threadIdx.x]);
}

__global__ void gscan_kernel(const int* __restrict__ gcnt, int* __restrict__ gbase,
                             int* __restrict__ gcur) {
    if (threadIdx.x == 0) {
        int run = 0;
        for (int g = 0; g < B_GRAPHS; ++g) {
            gbase[g] = run; gcur[g] = run;
            run += gcnt[g];
        }
        gbase[B_GRAPHS] = run;
    }
}

// ---------------------------------------------------------------------------
// Bucket edges by graph, packed local (src<<13 | dst). Coalesced flushes.
// ---------------------------------------------------------------------------
__global__ __launch_bounds__(256)
void bucket_kernel(const int* __restrict__ src, const int* __restrict__ dst,
                   int* __restrict__ gcur, int* __restrict__ binned) {
    __shared__ int bins[B_GRAPHS][BKT_CAP];
    __shared__ int bcnt[B_GRAPHS], sbase[B_GRAPHS], sn[B_GRAPHS];
    int tid = threadIdx.x;
    if (tid < B_GRAPHS) bcnt[tid] = 0;
    __syncthreads();
    int wgbase = blockIdx.x * 2048;
    for (int sub = 0; sub < 2; ++sub) {
        int e0 = wgbase + sub * 1024 + tid * 4;
        int4 s4 = *(const int4*)&src[e0];
        int4 d4 = *(const int4*)&dst[e0];
        int ss[4] = {s4.x, s4.y, s4.z, s4.w};
        int dd[4] = {d4.x, d4.y, d4.z, d4.w};
        #pragma unroll
        for (int k = 0; k < 4; ++k) {
            int b = dd[k] >> 13;
            int pk = ((ss[k] & 8191) << 13) | (dd[k] & 8191);
            int pos = atomicAdd(&bcnt[b], 1);
            if (pos < BKT_CAP) bins[b][pos] = pk;
            else { int gp = atomicAdd(&gcur[b], 1); binned[gp] = pk; }
        }
        __syncthreads();
        if (tid < B_GRAPHS) {
            int nb = min(bcnt[tid], BKT_CAP);
            sn[tid] = nb;
            sbase[tid] = atomicAdd(&gcur[tid], nb);
        }
        __syncthreads();
        int b = tid >> 3, r = tid & 7;
        for (int k = r; k < sn[b]; k += 8) binned[sbase[b] + k] = bins[b][k];
        __syncthreads();
        if (tid < B_GRAPHS) bcnt[tid] = 0;
        __syncthreads();
    }
}

// ---------------------------------------------------------------------------
// Parallel chunked counting sort (hist -> global scan -> fill), 8 chunks/graph.
// ---------------------------------------------------------------------------
template<int BINS, int LEVB>
__global__ __launch_bounds__(1024)
void sort_hist_kernel(const int* __restrict__ binned, const int* __restrict__ gbase,
                      const int* __restrict__ gend, const int* __restrict__ c1,
                      int* __restrict__ H) {
    __shared__ int hist[BINS];
    int wg = blockIdx.x, g = wg >> 3, sub = wg & 7, t = threadIdx.x;
    for (int i = t; i < BINS; i += 1024) hist[i] = 0;
    __syncthreads();
    int segb = gbase[g], sege = gend[g];
    int csz = (sege - segb + CPG - 1) / CPG;
    int e0 = segb + sub * csz, e1 = min(e0 + csz, sege);
    int nodeb = g * NPG;
    for (int e = e0 + t; e < e1; e += 1024) {
        int pk = binned[e];
        if (LEVB) {
            int sc = c1[nodeb + (pk >> 13)];
            int dc = c1[nodeb + (pk & 8191)];
            if (sc != dc) atomicAdd(&hist[dc & (BINS - 1)], 1);
        } else {
            atomicAdd(&hist[(pk & 8191) >> 4], 1);
        }
    }
    __syncthreads();
    for (int b = t; b < BINS; b += 1024)
        H[(size_t)(g * BINS + b) * CPG + sub] = hist[b];
}

template<int BINS, int LEVB>
__global__ __launch_bounds__(1024)
void sort_fill_kernel(const int* __restrict__ binned, const int* __restrict__ gbase,
                      const int* __restrict__ gend, const int* __restrict__ c1,
                      const int* __restrict__ S, int* __restrict__ outv) {
    __shared__ int cur[BINS];
    int wg = blockIdx.x, g = wg >> 3, sub = wg & 7, t = threadIdx.x;
    for (int b = t; b < BINS; b += 1024)
        cur[b] = S[(size_t)(g * BINS + b) * CPG + sub];
    __syncthreads();
    int segb = gbase[g], sege = gend[g];
    int csz = (sege - segb + CPG - 1) / CPG;
    int e0 = segb + sub * csz, e1 = min(e0 + csz, sege);
    int nodeb = g * NPG;
    for (int e = e0 + t; e < e1; e += 1024) {
        int pk = binned[e];
        if (LEVB) {
            int sc = c1[nodeb + (pk >> 13)];
            int dc = c1[nodeb + (pk & 8191)];
            if (sc != dc) {
                int p = atomicAdd(&cur[dc & (BINS - 1)], 1);
                outv[p] = sc;
            }
        } else {
            int p = atomicAdd(&cur[(pk & 8191) >> 4], 1);
            outv[p] = pk;
        }
    }
}

// ---------------------------------------------------------------------------
// Hierarchical exclusive scan (n % 1024 == 0, nb up to ~2048).
// ---------------------------------------------------------------------------
__global__ __launch_bounds__(256)
void scan_reduce_kernel(const int* __restrict__ counts, int* __restrict__ blocksums) {
    int t = threadIdx.x;
    int4 v = *(const int4*)&counts[blockIdx.x * 1024 + t * 4];
    int s = v.x + v.y + v.z + v.w;
    #pragma unroll
    for (int off = 32; off > 0; off >>= 1) s += __shfl_xor(s, off, 64);
    __shared__ int ws[4];
    if ((t & 63) == 0) ws[t >> 6] = s;
    __syncthreads();
    if (t == 0) blocksums[blockIdx.x] = ws[0] + ws[1] + ws[2] + ws[3];
}

__global__ __launch_bounds__(256)
void scan_blocks_kernel(const int* __restrict__ blocksums, int* __restrict__ blockpref,
                        int* __restrict__ offsets, int nb, int n) {
    __shared__ int sh[256];
    int t = threadIdx.x;
    int C = (nb + 255) / 256;
    int base = t * C;
    int s = 0;
    for (int i = 0; i < C; ++i) { int idx = base + i; if (idx < nb) s += blocksums[idx]; }
    sh[t] = s;
    __syncthreads();
    #pragma unroll
    for (int d = 1; d < 256; d <<= 1) {
        int u = (t >= d) ? sh[t - d] : 0;
        __syncthreads();
        sh[t] += u;
        __syncthreads();
    }
    int run = sh[t] - s;
    for (int i = 0; i < C; ++i) {
        int idx = base + i;
        if (idx < nb) { int v = blocksums[idx]; blockpref[idx] = run; run += v; }
    }
    if (t == 255) offsets[n] = sh[255];
}

__global__ __launch_bounds__(256)
void scan_write_kernel(const int* __restrict__ counts, const int* __restrict__ blockpref,
                       int* __restrict__ offsets, int* __restrict__ cursor) {
    int b = blockIdx.x, t = threadIdx.x;
    int base = b * 1024 + t * 4;
    int4 v = *(const int4*)&counts[base];
    int s = v.x + v.y + v.z + v.w;
    __shared__ int sh[256];
    sh[t] = s;
    __syncthreads();
    #pragma unroll
    for (int d = 1; d < 256; d <<= 1) {
        int u = (t >= d) ? sh[t - d] : 0;
        __syncthreads();
        sh[t] += u;
        __syncthreads();
    }
    int pref = blockpref[b] + sh[t] - s;
    int4 o;
    o.x = pref;
    o.y = pref + v.x;
    o.z = o.y + v.y;
    o.w = o.z + v.z;
    *(int4*)&offsets[base] = o;
    if (cursor) *(int4*)&cursor[base] = o;
}

// ---------------------------------------------------------------------------
// Level-A fused conv1+pool1: one wg per 16-dst bucket; per-(dst,ch) LDS
// atomicMax slots with order-preserving uint keys. 512 threads = 32 edge
// streams x 16 ch.
// ---------------------------------------------------------------------------
__global__ __launch_bounds__(512)
void gatherA_kernel(const float* __restrict__ a, const float* __restrict__ pos,
                    const float* __restrict__ Wp, const int* __restrict__ S,
                    const int* __restrict__ sortedA, const int* __restrict__ c1,
                    float* __restrict__ hp1) {
    __shared__ unsigned slot[256];
    int bid = blockIdx.x;
    int v = (bid & 7) * (B_GRAPHS * 512 / 8) + (bid >> 3);   // XCD-contiguous graphs
    int g = v >> 9;
    int t = threadIdx.x;
    if (t < 256) slot[t] = 0u;
    __syncthreads();
    int start = S[(size_t)v * CPG], end = S[(size_t)(v + 1) * CPG];
    int nodeb = g * NPG;
    int ch = t & 15, el = t >> 4;        // 32 edge streams
    for (int j = start + el; j < end; j += 32) {
        int pk = sortedA[j];
        float val = a[(size_t)(nodeb + (pk >> 13)) * 16 + ch];
        unsigned u = __float_as_uint(val);
        unsigned key = (u & 0x80000000u) ? ~u : (u | 0x80000000u);
        atomicMax(&slot[((pk & 15) << 4) + ch], key);
    }
    __syncthreads();
    if (t < 256) {
        int dl = t >> 4;
        unsigned k = slot[(dl << 4) + ch];
        if (k) {
            unsigned u = (k & 0x80000000u) ? (k ^ 0x80000000u) : ~k;
            float m = __uint_as_float(u);
            int dst = nodeb + ((v & 511) << 4) + dl;
            float px = pos[dst * 3 + 0], py = pos[dst * 3 + 1];
            float val = fmaxf(m - (px * Wp[ch] + py * Wp[16 + ch]), 0.0f);
            if (val > 0.0f)
                atomicMax((int*)&hp1[(size_t)c1[dst] * 16 + ch], __float_as_int(val));
        }
    }
}

// ---------------------------------------------------------------------------
// Level-C dedupe bitmap (parallel): LDS bitmap per chunk, merge via atomicOr.
// ---------------------------------------------------------------------------
__global__ __launch_bounds__(1024)
void bitC_kernel(const int* __restrict__ binned, const int* __restrict__ gbase,
                 const int* __restrict__ gend, const int* __restrict__ c12,
                 unsigned* __restrict__ bitsG) {
    __shared__ unsigned bits[2048];
    int wg = blockIdx.x, g = wg >> 3, sub = wg & 7, t = threadIdx.x;
    for (int i = t; i < 2048; i += 1024) bits[i] = 0;
    __syncthreads();
    int segb = gbase[g], sege = gend[g];
    int csz = (sege - segb + CPG - 1) / CPG;
    int e0 = segb + sub * csz, e1 = min(e0 + csz, sege);
    int nodeb = g * NPG, clb = g * 256;
    for (int e = e0 + t; e < e1; e += 1024) {
        int pk = binned[e];
        int sc = c12[nodeb + (pk >> 13)] - clb;
        int dc = c12[nodeb + (pk & 8191)] - clb;
        if (sc != dc) atomicOr(&bits[(dc << 3) + (sc >> 5)], 1u << (sc & 31));
    }
    __syncthreads();
    for (int i = t; i < 2048; i += 1024) {
        unsigned wv = bits[i];
        if (wv) atomicOr(&bitsG[((size_t)g << 11) + i], wv);
    }
}

__global__ __launch_bounds__(256)
void popcC_kernel(const unsigned* __restrict__ bitsG, int* __restrict__ pc) {
    int i = blockIdx.x * 256 + threadIdx.x;
    int s = 0;
    #pragma unroll
    for (int k = 0; k < 8; ++k) s += __popc(bitsG[((size_t)i << 3) + k]);
    pc[i] = s;
}

__global__ __launch_bounds__(256)
void emitC_kernel(const unsigned* __restrict__ bitsG, const int* __restrict__ SC,
                  int* __restrict__ csrC) {
    int i = blockIdx.x * 256 + threadIdx.x;
    int clb = (i >> 8) << 8;
    int p = SC[i];
    #pragma unroll
    for (int w = 0; w < 8; ++w) {
        unsigned word = bitsG[((size_t)i << 3) + w];
        while (word) {
            int b = __ffs(word) - 1;
            word &= word - 1;
            csrC[p++] = clb + (w << 5) + b;
        }
    }
}

// ---------------------------------------------------------------------------
// Coarse gather-max conv (wave per node, FPL floats/lane, XCD-swizzled).
// MODE 0: float4 stores by ch-group lanes.
// MODE 1: wave-local LDS transpose -> channel-per-lane coalesced atomicMax.
// ---------------------------------------------------------------------------
template<int OUT, int MODE, int STRIDE, int FPL>
__global__ __launch_bounds__(512)
void gatherR_kernel(const float* __restrict__ a, const float* __restrict__ pos,
                    const float* __restrict__ Wp, const int* __restrict__ S,
                    const int* __restrict__ csr, const int* __restrict__ outmap,
                    float* __restrict__ out, int nblocks) {
    constexpr int CH = OUT / FPL;         // ch-group lanes per edge
    constexpr int ES = 64 / CH;           // edge streams per wave
    constexpr int NV = FPL / 4;           // float4s per lane
    int bid = blockIdx.x;
    int sb = (bid & 7) * (nblocks >> 3) + (bid >> 3);   // XCD-contiguous ranges
    int v = sb * 8 + (threadIdx.x >> 6);
    int lane = threadIdx.x & 63;
    int ch = lane % CH, s = lane / CH;
    int l = S[(size_t)v * STRIDE], h = S[(size_t)(v + 1) * STRIDE];
    float4 m[NV];
    #pragma unroll
    for (int q = 0; q < NV; ++q) m[q] = make_float4(-1e30f, -1e30f, -1e30f, -1e30f);
    for (int j = l + s; j < h; j += ES) {
        int sc = csr[j];
        const float4* ap = (const float4*)&a[(size_t)sc * OUT + ch * FPL];
        #pragma unroll
        for (int q = 0; q < NV; ++q) {
            float4 f = ap[q];
            m[q].x = fmaxf(m[q].x, f.x); m[q].y = fmaxf(m[q].y, f.y);
            m[q].z = fmaxf(m[q].z, f.z); m[q].w = fmaxf(m[q].w, f.w);
        }
    }
    #pragma unroll
    for (int st = CH; st < 64; st <<= 1) {
        #pragma unroll
        for (int q = 0; q < NV; ++q) {
            m[q].x = fmaxf(m[q].x, __shfl_xor(m[q].x, st, 64));
            m[q].y = fmaxf(m[q].y, __shfl_xor(m[q].y, st, 64));
            m[q].z = fmaxf(m[q].z, __shfl_xor(m[q].z, st, 64));
            m[q].w = fmaxf(m[q].w, __shfl_xor(m[q].w, st, 64));
        }
    }
    if (MODE == 0) {
        if (s == 0) {
            float px = pos[v * 3 + 0], py = pos[v * 3 + 1];
            bool ne = h > l;
            #pragma unroll
            for (int q = 0; q < NV; ++q) {
                float4 wx = *(const float4*)&Wp[ch * FPL + q * 4];
                float4 wy = *(const float4*)&Wp[OUT + ch * FPL + q * 4];
                float4 val;
                val.x = ne ? fmaxf(m[q].x - (px * wx.x + py * wy.x), 0.0f) : 0.0f;
                val.y = ne ? fmaxf(m[q].y - (px * wx.y + py * wy.y), 0.0f) : 0.0f;
                val.z = ne ? fmaxf(m[q].z - (px * wx.z + py * wy.z), 0.0f) : 0.0f;
                val.w = ne ? fmaxf(m[q].w - (px * wx.w + py * wy.w), 0.0f) : 0.0f;
                *(float4*)&out[(size_t)v * OUT + ch * FPL + q * 4] = val;
            }
        }
    } else {
        // wave-local LDS transpose (written & read by the same wave: no barrier)
        __shared__ float red[8][OUT];
        int wid = threadIdx.x >> 6;
        if (s == 0) {
            #pragma unroll
            for (int q = 0; q < NV; ++q)
                *(float4*)&red[wid][ch * FPL + q * 4] = m[q];
        }
        if (lane < OUT) {
            float px = pos[v * 3 + 0], py = pos[v * 3 + 1];
            float val = red[wid][lane];
            float ct = px * Wp[lane] + py * Wp[OUT + lane];
            val = (h > l) ? fmaxf(val - ct, 0.0f) : 0.0f;
            if (val > 0.0f)
                atomicMax((int*)&out[(size_t)outmap[v] * OUT + lane], __float_as_int(val));
        }
    }
}

// ---------------------------------------------------------------------------
// Voxel cluster id + pos mean accumulation; finalize; out-cells; c12 compose.
// ---------------------------------------------------------------------------
__global__ __launch_bounds__(256)
void cluster_kernel(const float* __restrict__ pos, int* __restrict__ cluster,
                    float* __restrict__ psum, int* __restrict__ cnt,
                    int n, int batch_shift, float inv_grid, int cells) {
    int i = blockIdx.x * 256 + threadIdx.x;
    if (i >= n) return;
    float px = pos[i * 3 + 0], py = pos[i * 3 + 1], pz = pos[i * 3 + 2];
    int ix = min(max((int)floorf(px * inv_grid), 0), cells - 1);
    int iy = min(max((int)floorf(py * inv_grid), 0), cells - 1);
    int c = (i >> batch_shift) * cells * cells + iy * cells + ix;
    cluster[i] = c;
    atomicAdd(&psum[c * 3 + 0], px);
    atomicAdd(&psum[c * 3 + 1], py);
    atomicAdd(&psum[c * 3 + 2], pz);
    atomicAdd(&cnt[c], 1);
}

__global__ __launch_bounds__(256)
void posfin_kernel(const float* __restrict__ pos_sum, const int* __restrict__ cnt,
                   float* __restrict__ pos_new, int n_new) {
    int i = blockIdx.x * 256 + threadIdx.x;
    if (i >= n_new) return;
    float c = fmaxf((float)cnt[i], 1.0f);
    pos_new[i * 3 + 0] = pos_sum[i * 3 + 0] / c;
    pos_new[i * 3 + 1] = pos_sum[i * 3 + 1] / c;
    pos_new[i * 3 + 2] = pos_sum[i * 3 + 2] / c;
}

__global__ __launch_bounds__(256)
void cellout_kernel(const float* __restrict__ pos, int* __restrict__ cell, int n) {
    int i = blockIdx.x * 256 + threadIdx.x;
    if (i >= n) return;
    float px = pos[i * 3 + 0], py = pos[i * 3 + 1];
    int ix = min(max((int)floorf(px * (1.0f / 16.0f)), 0), 7);
    int iy = min(max((int)floorf(py * (1.0f / 16.0f)), 0), 7);
    cell[i] = (i >> 8) * 64 + iy * 8 + ix;
}

__global__ __launch_bounds__(256)
void c12map_kernel(const int* __restrict__ c1, const int* __restrict__ c2,
                   int* __restrict__ c12) {
    int i = blockIdx.x * 256 + threadIdx.x;
    if (i < N_NODES) c12[i] = c2[c1[i]];
}

// ---------------------------------------------------------------------------
// MLP head. mlp1 v3: grid (64 k-slabs x 4 col-tiles) = 256 blocks (1/CU).
// Block stages g-slab gs[64][32] (8 KB) in LDS (b-contiguous writes: no bank
// conflict), then thread-per-column: 64 x {1 coalesced Wl1 load + 8 float4
// LDS broadcast reads + 32 FMA}. Epilogue: 32 coalesced atomicAdds.
// Wl1 read exactly once chip-wide (16 MB).
// ---------------------------------------------------------------------------
__global__ __launch_bounds__(256)
void mlp1_kernel(const float* __restrict__ g, const float* __restrict__ Wl1,
                 float* __restrict__ hid) {
    __shared__ float gs[64][32];
    int kc = blockIdx.x, oc = blockIdx.y, t = threadIdx.x;
    int kbase = kc * 64;
    // load slab: i = j*32 + b (consecutive t -> consecutive b: LDS-conflict-free)
    for (int i = t; i < 2048; i += 256) {
        int j = i >> 5, b = i & 31;
        gs[j][b] = g[b * 4096 + kbase + j];
    }
    __syncthreads();
    int col = oc * 256 + t;
    float acc[32];
    #pragma unroll
    for (int b = 0; b < 32; ++b) acc[b] = 0.0f;
    for (int j = 0; j < 64; ++j) {
        float wv = Wl1[(size_t)(kbase + j) * 1024 + col];
        const float4* gv = (const float4*)&gs[j][0];
        #pragma unroll
        for (int b4 = 0; b4 < 8; ++b4) {
            float4 f = gv[b4];   // same-address across lanes: broadcast
            acc[b4 * 4 + 0] += f.x * wv;
            acc[b4 * 4 + 1] += f.y * wv;
            acc[b4 * 4 + 2] += f.z * wv;
            acc[b4 * 4 + 3] += f.w * wv;
        }
    }
    #pragma unroll
    for (int b = 0; b < 32; ++b)
        atomicAdd(&hid[b * 1024 + col], acc[b]);
}

__global__ __launch_bounds__(64)
void mlp2_kernel(const float* __restrict__ hid, const float* __restrict__ bl1,
                 const float* __restrict__ Wl2, const float* __restrict__ bl2,
                 float* __restrict__ out) {
    int b = blockIdx.x, l = threadIdx.x;
    float hv[16];
    #pragma unroll
    for (int i = 0; i < 16; ++i) {
        int idx = l + i * 64;
        hv[i] = fmaxf(hid[(size_t)b * 1024 + idx] + bl1[idx], 0.0f);
    }
    float logits[10];
    #pragma unroll
    for (int c = 0; c < 10; ++c) {
        float p = 0.0f;
        #pragma unroll
        for (int i = 0; i < 16; ++i)
            p += hv[i] * Wl2[(size_t)(l + i * 64) * 10 + c];
        #pragma unroll
        for (int off = 32; off > 0; off >>= 1) p += __shfl_xor(p, off, 64);
        logits[c] = p + bl2[c];
    }
    float m = logits[0];
    #pragma unroll
    for (int c = 1; c < 10; ++c) m = fmaxf(m, logits[c]);
    float ssum = 0.0f;
    #pragma unroll
    for (int c = 0; c < 10; ++c) ssum += expf(logits[c] - m);
    float lse = logf(ssum);
    if (l < 10) out[b * 10 + l] = logits[l] - m - lse;
}

// ---------------------------------------------------------------------------
extern "C" void kernel_launch(void* const* d_in, const int* in_sizes, int n_in,
                              void* d_out, int out_size, void* d_ws, size_t ws_size,
                              hipStream_t stream) {
    const float* x    = (const float*)d_in[0];
    const float* pos0 = (const float*)d_in[1];
    const int*   ei   = (const int*)d_in[2];
    const float* W1 = (const float*)d_in[4];  const float* b1 = (const float*)d_in[5];
    const float* W2 = (const float*)d_in[6];  const float* b2 = (const float*)d_in[7];
    const float* W3 = (const float*)d_in[8];  const float* b3 = (const float*)d_in[9];
    const float* W4 = (const float*)d_in[10]; const float* b4 = (const float*)d_in[11];
    const float* W5 = (const float*)d_in[12]; const float* b5 = (const float*)d_in[13];
    const float* Wl1 = (const float*)d_in[14]; const float* bl1 = (const float*)d_in[15];
    const float* Wl2 = (const float*)d_in[16]; const float* bl2 = (const float*)d_in[17];
    const int* src0 = ei;
    const int* dst0 = ei + NE;
    float* out = (float*)d_out;

    float* w = (float*)d_ws;
    size_t off = 0;
    auto alloc = [&](size_t n) { float* p = w + off; off += (n + 3) & ~(size_t)3; return p; };

    // --- zero-init region (one memset) ---
    int*      gcnt  = (int*)alloc(32);
    unsigned* bitsG = (unsigned*)alloc(B_GRAPHS * 2048);
    float* hp1   = alloc((size_t)N1 * 16);
    float* psum1 = alloc((size_t)N1 * 3);
    int*   icnt1 = (int*)alloc(N1);
    float* hp2   = alloc((size_t)N2 * 32);
    float* psum2 = alloc((size_t)N2 * 3);
    int*   icnt2 = (int*)alloc(N2);
    float* g     = alloc((size_t)B_GRAPHS * 4096);
    float* hid   = alloc((size_t)B_GRAPHS * 1024);
    size_t zero_bytes = off * sizeof(float);
    // --- abuf (a at every level) ---
    float* abuf = alloc((size_t)N_NODES * 16);
    // --- union 1: binned (dead after bitC) -> h2, h4 ---
    float* ubase = alloc((size_t)NE);
    int*   binned = (int*)ubase;
    float* h2 = ubase;
    float* h4 = h2 + (size_t)N1 * 32;
    // --- union 2: sortedA (dead after gatherA) -> csrC (written by emitC) ---
    int* sortedA = (int*)alloc(NE);
    int* csrC = sortedA;
    // --- rest ---
    int* csrB = (int*)alloc(NE);
    int* H   = (int*)alloc((size_t)B_GRAPHS * 1024 * CPG + 4);
    int* S_A = (int*)alloc((size_t)B_GRAPHS * 512 * CPG + 4);
    int* S_B = (int*)alloc((size_t)B_GRAPHS * 1024 * CPG + 4);
    int* pc  = (int*)alloc(N2);
    int* SC  = (int*)alloc(N2 + 4);
    float* pos1 = alloc((size_t)N1 * 3);
    float* pos2 = alloc((size_t)N2 * 3);
    int* cell = (int*)alloc(N2);
    int* c1   = (int*)alloc(N_NODES);
    int* c2   = (int*)alloc(N1);
    int* c12  = (int*)alloc(N_NODES);
    int* gbase = (int*)alloc(64);
    int* gcur  = (int*)alloc(64);
    int* blocksums = (int*)alloc(2560);
    int* blockpref = (int*)alloc(2560);
    (void)ws_size; (void)in_sizes; (void)n_in; (void)out_size;

    hipMemsetAsync(d_ws, 0, zero_bytes, stream);

    auto hscan = [&](const int* cnts, int* offs, int n) {
        scan_reduce_kernel<<<n / 1024, 256, 0, stream>>>(cnts, blocksums);
        scan_blocks_kernel<<<1, 256, 0, stream>>>(blocksums, blockpref, offs, n / 1024, n);
        scan_write_kernel<<<n / 1024, 256, 0, stream>>>(cnts, blockpref, offs, nullptr);
    };

    // ===== level A: bucket by graph, bucket-16 sort, fused conv1+pool1 =====
    node_a_kernel<1, 16><<<N_NODES / 256, 256, 0, stream>>>(x, pos0, W1, b1, abuf, N_NODES);
    precount_kernel<<<256, 256, 0, stream>>>(dst0, gcnt);
    gscan_kernel<<<1, 64, 0, stream>>>(gcnt, gbase, gcur);
    bucket_kernel<<<NE / 2048, 256, 0, stream>>>(src0, dst0, gcur, binned);
    sort_hist_kernel<512, 0><<<B_GRAPHS * CPG, 1024, 0, stream>>>(binned, gbase, gcur, nullptr, H);
    hscan(H, S_A, B_GRAPHS * 512 * CPG);
    sort_fill_kernel<512, 0><<<B_GRAPHS * CPG, 1024, 0, stream>>>(binned, gbase, gcur, nullptr, S_A, sortedA);
    cluster_kernel<<<N_NODES / 256, 256, 0, stream>>>(pos0, c1, psum1, icnt1, N_NODES, 13, 0.25f, 32);
    gatherA_kernel<<<B_GRAPHS * 512, 512, 0, stream>>>(abuf, pos0, W1 + 16, S_A, sortedA, c1, hp1);
    posfin_kernel<<<N1 / 256, 256, 0, stream>>>(psum1, icnt1, pos1, N1);

    // ===== cluster maps =====
    cluster_kernel<<<N1 / 256, 256, 0, stream>>>(pos1, c2, psum2, icnt2, N1, 10, 0.125f, 16);
    posfin_kernel<<<N2 / 256, 256, 0, stream>>>(psum2, icnt2, pos2, N2);
    c12map_kernel<<<N_NODES / 256, 256, 0, stream>>>(c1, c2, c12);

    // ===== level-B CSR (1024-bin counting sort) =====
    sort_hist_kernel<1024, 1><<<B_GRAPHS * CPG, 1024, 0, stream>>>(binned, gbase, gcur, c1, H);
    hscan(H, S_B, B_GRAPHS * 1024 * CPG);
    sort_fill_kernel<1024, 1><<<B_GRAPHS * CPG, 1024, 0, stream>>>(binned, gbase, gcur, c1, S_B, csrB);

    // ===== level-C CSR (parallel bitmap dedupe; csrC aliases dead sortedA) =====
    bitC_kernel<<<B_GRAPHS * CPG, 1024, 0, stream>>>(binned, gbase, gcur, c12, bitsG);
    popcC_kernel<<<N2 / 256, 256, 0, stream>>>(bitsG, pc);
    hscan(pc, SC, N2);
    emitC_kernel<<<N2 / 256, 256, 0, stream>>>(bitsG, SC, csrC);

    // ===== level B: conv2 (store), conv3 (fused pool2) =====
    node_a_kernel<16, 32><<<N1 / 256, 256, 0, stream>>>(hp1, pos1, W2, b2, abuf, N1);
    gatherR_kernel<32, 0, CPG, 8><<<N1 / 8, 512, 0, stream>>>(abuf, pos1, W2 + 512, S_B, csrB, nullptr, h2, N1 / 8);
    node_a_kernel<32, 32><<<N1 / 256, 256, 0, stream>>>(h2, pos1, W3, b3, abuf, N1);
    gatherR_kernel<32, 1, CPG, 8><<<N1 / 8, 512, 0, stream>>>(abuf, pos1, W3 + 1024, S_B, csrB, c2, hp2, N1 / 8);

    // ===== level C: conv4 (store), conv5 (fused pool_out) =====
    node_a_kernel<32, 64><<<N2 / 256, 256, 0, stream>>>(hp2, pos2, W4, b4, abuf, N2);
    gatherR_kernel<64, 0, 1, 16><<<N2 / 8, 512, 0, stream>>>(abuf, pos2, W4 + 2048, SC, csrC, nullptr, h4, N2 / 8);
    node_a_kernel<64, 64><<<N2 / 256, 256, 0, stream>>>(h4, pos2, W5, b5, abuf, N2);
    cellout_kernel<<<N2 / 256, 256, 0, stream>>>(pos2, cell, N2);
    gatherR_kernel<64, 1, 1, 16><<<N2 / 8, 512, 0, stream>>>(abuf, pos2, W5 + 4096, SC, csrC, cell, g, N2 / 8);

    // ===== MLP head =====
    mlp1_kernel<<<dim3(64, 4), 256, 0, stream>>>(g, Wl1, hid);
    mlp2_kernel<<<32, 64, 0, stream>>>(hid, bl1, Wl2, bl2, out);
}

// Round 13
// 464.379 us; speedup vs baseline: 1.1739x; 1.0616x over previous
//
#include <hip/hip_runtime.h>
#include <cstdint>
#include <cstddef>

#define B_GRAPHS 32
#define NPG      8192
#define N_NODES  (B_GRAPHS * NPG)   // 262144
#define DEG      8
#define NE       (N_NODES * DEG)    // 2097152
#define N1       32768              // B * 32*32  (grid 4)
#define N2       8192               // B * 16*16  (grid 8)
#define BKT_CAP  80
#define CPG      8                  // chunks per graph for parallel sorts

// ---------------------------------------------------------------------------
// Node-level precompute: a[i,o] = b[o] + sum_k h[i,k]*W[k,o] + px*W[IN,o] + py*W[IN+1,o]
// ---------------------------------------------------------------------------
template<int IN, int OUT>
__global__ __launch_bounds__(256)
void node_a_kernel(const float* __restrict__ h, const float* __restrict__ pos,
                   const float* __restrict__ W, const float* __restrict__ bias,
                   float* __restrict__ a, int n) {
    constexpr int FEAT = IN + 2;
    __shared__ float Ws[FEAT * OUT + OUT];
    for (int i = threadIdx.x; i < FEAT * OUT; i += 256) Ws[i] = W[i];
    for (int i = threadIdx.x; i < OUT; i += 256) Ws[FEAT * OUT + i] = bias[i];
    __syncthreads();
    int i = blockIdx.x * 256 + threadIdx.x;
    if (i >= n) return;

    float acc[OUT];
    #pragma unroll
    for (int o = 0; o < OUT; ++o) acc[o] = Ws[FEAT * OUT + o];

    float px = pos[i * 3 + 0], py = pos[i * 3 + 1];
    #pragma unroll
    for (int o = 0; o < OUT; ++o)
        acc[o] += px * Ws[IN * OUT + o] + py * Ws[(IN + 1) * OUT + o];

    if constexpr (IN % 4 == 0) {
        const float4* h4 = (const float4*)(h + (size_t)i * IN);
        for (int k4 = 0; k4 < IN / 4; ++k4) {
            float4 f = h4[k4];
            #pragma unroll
            for (int o = 0; o < OUT; ++o) {
                acc[o] += f.x * Ws[(k4 * 4 + 0) * OUT + o];
                acc[o] += f.y * Ws[(k4 * 4 + 1) * OUT + o];
                acc[o] += f.z * Ws[(k4 * 4 + 2) * OUT + o];
                acc[o] += f.w * Ws[(k4 * 4 + 3) * OUT + o];
            }
        }
    } else {
        for (int k = 0; k < IN; ++k) {
            float f = h[(size_t)i * IN + k];
            #pragma unroll
            for (int o = 0; o < OUT; ++o) acc[o] += f * Ws[k * OUT + o];
        }
    }
    float* ap = a + (size_t)i * OUT;
    #pragma unroll
    for (int o = 0; o < OUT; ++o) ap[o] = acc[o];
}

// ---------------------------------------------------------------------------
// Per-graph edge histogram (gcnt zeroed) + tiny serial scan.
// ---------------------------------------------------------------------------
__global__ __launch_bounds__(256)
void precount_kernel(const int* __restrict__ dst, int* __restrict__ gcnt) {
    __shared__ int hist[B_GRAPHS];
    if (threadIdx.x < B_GRAPHS) hist[threadIdx.x] = 0;
    __syncthreads();
    int gid = blockIdx.x * 256 + threadIdx.x;
    for (int e = gid; e < NE; e += 256 * 256)
        atomicAdd(&hist[dst[e] >> 13], 1);
    __syncthreads();
    if (threadIdx.x < B_GRAPHS) atomicAdd(&gcnt[threadIdx.x], hist[threadIdx.x]);
}

__global__ void gscan_kernel(const int* __restrict__ gcnt, int* __restrict__ gbase,
                             int* __restrict__ gcur) {
    if (threadIdx.x == 0) {
        int run = 0;
        for (int g = 0; g < B_GRAPHS; ++g) {
            gbase[g] = run; gcur[g] = run;
            run += gcnt[g];
        }
        gbase[B_GRAPHS] = run;
    }
}

// ---------------------------------------------------------------------------
// Bucket edges by graph, packed local (src<<13 | dst). Coalesced flushes.
// ---------------------------------------------------------------------------
__global__ __launch_bounds__(256)
void bucket_kernel(const int* __restrict__ src, const int* __restrict__ dst,
                   int* __restrict__ gcur, int* __restrict__ binned) {
    __shared__ int bins[B_GRAPHS][BKT_CAP];
    __shared__ int bcnt[B_GRAPHS], sbase[B_GRAPHS], sn[B_GRAPHS];
    int tid = threadIdx.x;
    if (tid < B_GRAPHS) bcnt[tid] = 0;
    __syncthreads();
    int wgbase = blockIdx.x * 2048;
    for (int sub = 0; sub < 2; ++sub) {
        int e0 = wgbase + sub * 1024 + tid * 4;
        int4 s4 = *(const int4*)&src[e0];
        int4 d4 = *(const int4*)&dst[e0];
        int ss[4] = {s4.x, s4.y, s4.z, s4.w};
        int dd[4] = {d4.x, d4.y, d4.z, d4.w};
        #pragma unroll
        for (int k = 0; k < 4; ++k) {
            int b = dd[k] >> 13;
            int pk = ((ss[k] & 8191) << 13) | (dd[k] & 8191);
            int pos = atomicAdd(&bcnt[b], 1);
            if (pos < BKT_CAP) bins[b][pos] = pk;
            else { int gp = atomicAdd(&gcur[b], 1); binned[gp] = pk; }
        }
        __syncthreads();
        if (tid < B_GRAPHS) {
            int nb = min(bcnt[tid], BKT_CAP);
            sn[tid] = nb;
            sbase[tid] = atomicAdd(&gcur[tid], nb);
        }
        __syncthreads();
        int b = tid >> 3, r = tid & 7;
        for (int k = r; k < sn[b]; k += 8) binned[sbase[b] + k] = bins[b][k];
        __syncthreads();
        if (tid < B_GRAPHS) bcnt[tid] = 0;
        __syncthreads();
    }
}

// ---------------------------------------------------------------------------
// Parallel chunked counting sort (hist -> global scan -> fill), 8 chunks/graph.
// ---------------------------------------------------------------------------
template<int BINS, int LEVB>
__global__ __launch_bounds__(1024)
void sort_hist_kernel(const int* __restrict__ binned, const int* __restrict__ gbase,
                      const int* __restrict__ gend, const int* __restrict__ c1,
                      int* __restrict__ H) {
    __shared__ int hist[BINS];
    int wg = blockIdx.x, g = wg >> 3, sub = wg & 7, t = threadIdx.x;
    for (int i = t; i < BINS; i += 1024) hist[i] = 0;
    __syncthreads();
    int segb = gbase[g], sege = gend[g];
    int csz = (sege - segb + CPG - 1) / CPG;
    int e0 = segb + sub * csz, e1 = min(e0 + csz, sege);
    int nodeb = g * NPG;
    for (int e = e0 + t; e < e1; e += 1024) {
        int pk = binned[e];
        if (LEVB) {
            int sc = c1[nodeb + (pk >> 13)];
            int dc = c1[nodeb + (pk & 8191)];
            if (sc != dc) atomicAdd(&hist[dc & (BINS - 1)], 1);
        } else {
            atomicAdd(&hist[(pk & 8191) >> 4], 1);
        }
    }
    __syncthreads();
    for (int b = t; b < BINS; b += 1024)
        H[(size_t)(g * BINS + b) * CPG + sub] = hist[b];
}

template<int BINS, int LEVB>
__global__ __launch_bounds__(1024)
void sort_fill_kernel(const int* __restrict__ binned, const int* __restrict__ gbase,
                      const int* __restrict__ gend, const int* __restrict__ c1,
                      const int* __restrict__ S, int* __restrict__ outv) {
    __shared__ int cur[BINS];
    int wg = blockIdx.x, g = wg >> 3, sub = wg & 7, t = threadIdx.x;
    for (int b = t; b < BINS; b += 1024)
        cur[b] = S[(size_t)(g * BINS + b) * CPG + sub];
    __syncthreads();
    int segb = gbase[g], sege = gend[g];
    int csz = (sege - segb + CPG - 1) / CPG;
    int e0 = segb + sub * csz, e1 = min(e0 + csz, sege);
    int nodeb = g * NPG;
    for (int e = e0 + t; e < e1; e += 1024) {
        int pk = binned[e];
        if (LEVB) {
            int sc = c1[nodeb + (pk >> 13)];
            int dc = c1[nodeb + (pk & 8191)];
            if (sc != dc) {
                int p = atomicAdd(&cur[dc & (BINS - 1)], 1);
                outv[p] = sc;
            }
        } else {
            int p = atomicAdd(&cur[(pk & 8191) >> 4], 1);
            outv[p] = pk;
        }
    }
}

// ---------------------------------------------------------------------------
// Hierarchical exclusive scan (n % 1024 == 0, nb up to ~2048).
// ---------------------------------------------------------------------------
__global__ __launch_bounds__(256)
void scan_reduce_kernel(const int* __restrict__ counts, int* __restrict__ blocksums) {
    int t = threadIdx.x;
    int4 v = *(const int4*)&counts[blockIdx.x * 1024 + t * 4];
    int s = v.x + v.y + v.z + v.w;
    #pragma unroll
    for (int off = 32; off > 0; off >>= 1) s += __shfl_xor(s, off, 64);
    __shared__ int ws[4];
    if ((t & 63) == 0) ws[t >> 6] = s;
    __syncthreads();
    if (t == 0) blocksums[blockIdx.x] = ws[0] + ws[1] + ws[2] + ws[3];
}

__global__ __launch_bounds__(256)
void scan_blocks_kernel(const int* __restrict__ blocksums, int* __restrict__ blockpref,
                        int* __restrict__ offsets, int nb, int n) {
    __shared__ int sh[256];
    int t = threadIdx.x;
    int C = (nb + 255) / 256;
    int base = t * C;
    int s = 0;
    for (int i = 0; i < C; ++i) { int idx = base + i; if (idx < nb) s += blocksums[idx]; }
    sh[t] = s;
    __syncthreads();
    #pragma unroll
    for (int d = 1; d < 256; d <<= 1) {
        int u = (t >= d) ? sh[t - d] : 0;
        __syncthreads();
        sh[t] += u;
        __syncthreads();
    }
    int run = sh[t] - s;
    for (int i = 0; i < C; ++i) {
        int idx = base + i;
        if (idx < nb) { int v = blocksums[idx]; blockpref[idx] = run; run += v; }
    }
    if (t == 255) offsets[n] = sh[255];
}

__global__ __launch_bounds__(256)
void scan_write_kernel(const int* __restrict__ counts, const int* __restrict__ blockpref,
                       int* __restrict__ offsets, int* __restrict__ cursor) {
    int b = blockIdx.x, t = threadIdx.x;
    int base = b * 1024 + t * 4;
    int4 v = *(const int4*)&counts[base];
    int s = v.x + v.y + v.z + v.w;
    __shared__ int sh[256];
    sh[t] = s;
    __syncthreads();
    #pragma unroll
    for (int d = 1; d < 256; d <<= 1) {
        int u = (t >= d) ? sh[t - d] : 0;
        __syncthreads();
        sh[t] += u;
        __syncthreads();
    }
    int pref = blockpref[b] + sh[t] - s;
    int4 o;
    o.x = pref;
    o.y = pref + v.x;
    o.z = o.y + v.y;
    o.w = o.z + v.z;
    *(int4*)&offsets[base] = o;
    if (cursor) *(int4*)&cursor[base] = o;
}

// ---------------------------------------------------------------------------
// Level-A fused conv1+pool1: one wg per 16-dst bucket; per-(dst,ch) LDS
// atomicMax slots with order-preserving uint keys. 512 threads = 32 edge
// streams x 16 ch. Inner loop unrolled x4 with batched prefetch: 4 pk loads,
// then 4 a-row loads (all independent), then 4 LDS atomics — breaks the
// serial load->atomic chain that bounded round-12's 62us. Out-of-range
// entries duplicate the last edge (max is idempotent -> no guards).
// ---------------------------------------------------------------------------
__global__ __launch_bounds__(512)
void gatherA_kernel(const float* __restrict__ a, const float* __restrict__ pos,
                    const float* __restrict__ Wp, const int* __restrict__ S,
                    const int* __restrict__ sortedA, const int* __restrict__ c1,
                    float* __restrict__ hp1) {
    __shared__ unsigned slot[256];
    int bid = blockIdx.x;
    int v = (bid & 7) * (B_GRAPHS * 512 / 8) + (bid >> 3);   // XCD-contiguous graphs
    int g = v >> 9;
    int t = threadIdx.x;
    if (t < 256) slot[t] = 0u;
    __syncthreads();
    int start = S[(size_t)v * CPG], end = S[(size_t)(v + 1) * CPG];
    int nodeb = g * NPG;
    int ch = t & 15, el = t >> 4;        // 32 edge streams
    for (int j = start + el; j < end; j += 128) {
        int pk[4];
        float vv[4];
        #pragma unroll
        for (int u = 0; u < 4; ++u) {
            int jj = j + u * 32;
            pk[u] = sortedA[jj < end ? jj : end - 1];
        }
        #pragma unroll
        for (int u = 0; u < 4; ++u)
            vv[u] = a[(size_t)(nodeb + (pk[u] >> 13)) * 16 + ch];
        #pragma unroll
        for (int u = 0; u < 4; ++u) {
            unsigned uu = __float_as_uint(vv[u]);
            unsigned key = (uu & 0x80000000u) ? ~uu : (uu | 0x80000000u);
            atomicMax(&slot[((pk[u] & 15) << 4) + ch], key);
        }
    }
    __syncthreads();
    if (t < 256) {
        int dl = t >> 4;
        unsigned k = slot[(dl << 4) + ch];
        if (k) {
            unsigned u = (k & 0x80000000u) ? (k ^ 0x80000000u) : ~k;
            float m = __uint_as_float(u);
            int dst = nodeb + ((v & 511) << 4) + dl;
            float px = pos[dst * 3 + 0], py = pos[dst * 3 + 1];
            float val = fmaxf(m - (px * Wp[ch] + py * Wp[16 + ch]), 0.0f);
            if (val > 0.0f)
                atomicMax((int*)&hp1[(size_t)c1[dst] * 16 + ch], __float_as_int(val));
        }
    }
}

// ---------------------------------------------------------------------------
// Level-C dedupe bitmap (parallel): LDS bitmap per chunk, merge via atomicOr.
// ---------------------------------------------------------------------------
__global__ __launch_bounds__(1024)
void bitC_kernel(const int* __restrict__ binned, const int* __restrict__ gbase,
                 const int* __restrict__ gend, const int* __restrict__ c12,
                 unsigned* __restrict__ bitsG) {
    __shared__ unsigned bits[2048];
    int wg = blockIdx.x, g = wg >> 3, sub = wg & 7, t = threadIdx.x;
    for (int i = t; i < 2048; i += 1024) bits[i] = 0;
    __syncthreads();
    int segb = gbase[g], sege = gend[g];
    int csz = (sege - segb + CPG - 1) / CPG;
    int e0 = segb + sub * csz, e1 = min(e0 + csz, sege);
    int nodeb = g * NPG, clb = g * 256;
    for (int e = e0 + t; e < e1; e += 1024) {
        int pk = binned[e];
        int sc = c12[nodeb + (pk >> 13)] - clb;
        int dc = c12[nodeb + (pk & 8191)] - clb;
        if (sc != dc) atomicOr(&bits[(dc << 3) + (sc >> 5)], 1u << (sc & 31));
    }
    __syncthreads();
    for (int i = t; i < 2048; i += 1024) {
        unsigned wv = bits[i];
        if (wv) atomicOr(&bitsG[((size_t)g << 11) + i], wv);
    }
}

__global__ __launch_bounds__(256)
void popcC_kernel(const unsigned* __restrict__ bitsG, int* __restrict__ pc) {
    int i = blockIdx.x * 256 + threadIdx.x;
    int s = 0;
    #pragma unroll
    for (int k = 0; k < 8; ++k) s += __popc(bitsG[((size_t)i << 3) + k]);
    pc[i] = s;
}

__global__ __launch_bounds__(256)
void emitC_kernel(const unsigned* __restrict__ bitsG, const int* __restrict__ SC,
                  int* __restrict__ csrC) {
    int i = blockIdx.x * 256 + threadIdx.x;
    int clb = (i >> 8) << 8;
    int p = SC[i];
    #pragma unroll
    for (int w = 0; w < 8; ++w) {
        unsigned word = bitsG[((size_t)i << 3) + w];
        while (word) {
            int b = __ffs(word) - 1;
            word &= word - 1;
            csrC[p++] = clb + (w << 5) + b;
        }
    }
}

// ---------------------------------------------------------------------------
// Coarse gather-max conv (wave per node, FPL floats/lane, XCD-swizzled).
// Inner loop unrolled x2 (duplicate-edge trick, max idempotent) so both csr
// and both a-row loads issue before the fmax chain.
// MODE 0: float4 stores by ch-group lanes.
// MODE 1: wave-local LDS transpose -> channel-per-lane coalesced atomicMax.
// ---------------------------------------------------------------------------
template<int OUT, int MODE, int STRIDE, int FPL>
__global__ __launch_bounds__(512)
void gatherR_kernel(const float* __restrict__ a, const float* __restrict__ pos,
                    const float* __restrict__ Wp, const int* __restrict__ S,
                    const int* __restrict__ csr, const int* __restrict__ outmap,
                    float* __restrict__ out, int nblocks) {
    constexpr int CH = OUT / FPL;         // ch-group lanes per edge
    constexpr int ES = 64 / CH;           // edge streams per wave
    constexpr int NV = FPL / 4;           // float4s per lane
    int bid = blockIdx.x;
    int sb = (bid & 7) * (nblocks >> 3) + (bid >> 3);   // XCD-contiguous ranges
    int v = sb * 8 + (threadIdx.x >> 6);
    int lane = threadIdx.x & 63;
    int ch = lane % CH, s = lane / CH;
    int l = S[(size_t)v * STRIDE], h = S[(size_t)(v + 1) * STRIDE];
    float4 m[NV];
    #pragma unroll
    for (int q = 0; q < NV; ++q) m[q] = make_float4(-1e30f, -1e30f, -1e30f, -1e30f);
    for (int j = l + s; j < h; j += 2 * ES) {
        int j1 = j + ES;
        int sc0 = csr[j];
        int sc1 = csr[j1 < h ? j1 : j];   // duplicate edge if past end (max-idempotent)
        const float4* ap0 = (const float4*)&a[(size_t)sc0 * OUT + ch * FPL];
        const float4* ap1 = (const float4*)&a[(size_t)sc1 * OUT + ch * FPL];
        #pragma unroll
        for (int q = 0; q < NV; ++q) {
            float4 f0 = ap0[q];
            float4 f1 = ap1[q];
            m[q].x = fmaxf(m[q].x, fmaxf(f0.x, f1.x));
            m[q].y = fmaxf(m[q].y, fmaxf(f0.y, f1.y));
            m[q].z = fmaxf(m[q].z, fmaxf(f0.z, f1.z));
            m[q].w = fmaxf(m[q].w, fmaxf(f0.w, f1.w));
        }
    }
    #pragma unroll
    for (int st = CH; st < 64; st <<= 1) {
        #pragma unroll
        for (int q = 0; q < NV; ++q) {
            m[q].x = fmaxf(m[q].x, __shfl_xor(m[q].x, st, 64));
            m[q].y = fmaxf(m[q].y, __shfl_xor(m[q].y, st, 64));
            m[q].z = fmaxf(m[q].z, __shfl_xor(m[q].z, st, 64));
            m[q].w = fmaxf(m[q].w, __shfl_xor(m[q].w, st, 64));
        }
    }
    if (MODE == 0) {
        if (s == 0) {
            float px = pos[v * 3 + 0], py = pos[v * 3 + 1];
            bool ne = h > l;
            #pragma unroll
            for (int q = 0; q < NV; ++q) {
                float4 wx = *(const float4*)&Wp[ch * FPL + q * 4];
                float4 wy = *(const float4*)&Wp[OUT + ch * FPL + q * 4];
                float4 val;
                val.x = ne ? fmaxf(m[q].x - (px * wx.x + py * wy.x), 0.0f) : 0.0f;
                val.y = ne ? fmaxf(m[q].y - (px * wx.y + py * wy.y), 0.0f) : 0.0f;
                val.z = ne ? fmaxf(m[q].z - (px * wx.z + py * wy.z), 0.0f) : 0.0f;
                val.w = ne ? fmaxf(m[q].w - (px * wx.w + py * wy.w), 0.0f) : 0.0f;
                *(float4*)&out[(size_t)v * OUT + ch * FPL + q * 4] = val;
            }
        }
    } else {
        // wave-local LDS transpose (written & read by the same wave: no barrier)
        __shared__ float red[8][OUT];
        int wid = threadIdx.x >> 6;
        if (s == 0) {
            #pragma unroll
            for (int q = 0; q < NV; ++q)
                *(float4*)&red[wid][ch * FPL + q * 4] = m[q];
        }
        if (lane < OUT) {
            float px = pos[v * 3 + 0], py = pos[v * 3 + 1];
            float val = red[wid][lane];
            float ct = px * Wp[lane] + py * Wp[OUT + lane];
            val = (h > l) ? fmaxf(val - ct, 0.0f) : 0.0f;
            if (val > 0.0f)
                atomicMax((int*)&out[(size_t)outmap[v] * OUT + lane], __float_as_int(val));
        }
    }
}

// ---------------------------------------------------------------------------
// Voxel cluster id + pos mean accumulation; finalize; out-cells; c12 compose.
// ---------------------------------------------------------------------------
__global__ __launch_bounds__(256)
void cluster_kernel(const float* __restrict__ pos, int* __restrict__ cluster,
                    float* __restrict__ psum, int* __restrict__ cnt,
                    int n, int batch_shift, float inv_grid, int cells) {
    int i = blockIdx.x * 256 + threadIdx.x;
    if (i >= n) return;
    float px = pos[i * 3 + 0], py = pos[i * 3 + 1], pz = pos[i * 3 + 2];
    int ix = min(max((int)floorf(px * inv_grid), 0), cells - 1);
    int iy = min(max((int)floorf(py * inv_grid), 0), cells - 1);
    int c = (i >> batch_shift) * cells * cells + iy * cells + ix;
    cluster[i] = c;
    atomicAdd(&psum[c * 3 + 0], px);
    atomicAdd(&psum[c * 3 + 1], py);
    atomicAdd(&psum[c * 3 + 2], pz);
    atomicAdd(&cnt[c], 1);
}

__global__ __launch_bounds__(256)
void posfin_kernel(const float* __restrict__ pos_sum, const int* __restrict__ cnt,
                   float* __restrict__ pos_new, int n_new) {
    int i = blockIdx.x * 256 + threadIdx.x;
    if (i >= n_new) return;
    float c = fmaxf((float)cnt[i], 1.0f);
    pos_new[i * 3 + 0] = pos_sum[i * 3 + 0] / c;
    pos_new[i * 3 + 1] = pos_sum[i * 3 + 1] / c;
    pos_new[i * 3 + 2] = pos_sum[i * 3 + 2] / c;
}

__global__ __launch_bounds__(256)
void cellout_kernel(const float* __restrict__ pos, int* __restrict__ cell, int n) {
    int i = blockIdx.x * 256 + threadIdx.x;
    if (i >= n) return;
    float px = pos[i * 3 + 0], py = pos[i * 3 + 1];
    int ix = min(max((int)floorf(px * (1.0f / 16.0f)), 0), 7);
    int iy = min(max((int)floorf(py * (1.0f / 16.0f)), 0), 7);
    cell[i] = (i >> 8) * 64 + iy * 8 + ix;
}

__global__ __launch_bounds__(256)
void c12map_kernel(const int* __restrict__ c1, const int* __restrict__ c2,
                   int* __restrict__ c12) {
    int i = blockIdx.x * 256 + threadIdx.x;
    if (i < N_NODES) c12[i] = c2[c1[i]];
}

// ---------------------------------------------------------------------------
// MLP head. mlp1 v3: grid (64 k-slabs x 4 col-tiles) = 256 blocks (1/CU).
// ---------------------------------------------------------------------------
__global__ __launch_bounds__(256)
void mlp1_kernel(const float* __restrict__ g, const float* __restrict__ Wl1,
                 float* __restrict__ hid) {
    __shared__ float gs[64][32];
    int kc = blockIdx.x, oc = blockIdx.y, t = threadIdx.x;
    int kbase = kc * 64;
    for (int i = t; i < 2048; i += 256) {
        int j = i >> 5, b = i & 31;
        gs[j][b] = g[b * 4096 + kbase + j];
    }
    __syncthreads();
    int col = oc * 256 + t;
    float acc[32];
    #pragma unroll
    for (int b = 0; b < 32; ++b) acc[b] = 0.0f;
    for (int j = 0; j < 64; ++j) {
        float wv = Wl1[(size_t)(kbase + j) * 1024 + col];
        const float4* gv = (const float4*)&gs[j][0];
        #pragma unroll
        for (int b4 = 0; b4 < 8; ++b4) {
            float4 f = gv[b4];
            acc[b4 * 4 + 0] += f.x * wv;
            acc[b4 * 4 + 1] += f.y * wv;
            acc[b4 * 4 + 2] += f.z * wv;
            acc[b4 * 4 + 3] += f.w * wv;
        }
    }
    #pragma unroll
    for (int b = 0; b < 32; ++b)
        atomicAdd(&hid[b * 1024 + col], acc[b]);
}

__global__ __launch_bounds__(64)
void mlp2_kernel(const float* __restrict__ hid, const float* __restrict__ bl1,
                 const float* __restrict__ Wl2, const float* __restrict__ bl2,
                 float* __restrict__ out) {
    int b = blockIdx.x, l = threadIdx.x;
    float hv[16];
    #pragma unroll
    for (int i = 0; i < 16; ++i) {
        int idx = l + i * 64;
        hv[i] = fmaxf(hid[(size_t)b * 1024 + idx] + bl1[idx], 0.0f);
    }
    float logits[10];
    #pragma unroll
    for (int c = 0; c < 10; ++c) {
        float p = 0.0f;
        #pragma unroll
        for (int i = 0; i < 16; ++i)
            p += hv[i] * Wl2[(size_t)(l + i * 64) * 10 + c];
        #pragma unroll
        for (int off = 32; off > 0; off >>= 1) p += __shfl_xor(p, off, 64);
        logits[c] = p + bl2[c];
    }
    float m = logits[0];
    #pragma unroll
    for (int c = 1; c < 10; ++c) m = fmaxf(m, logits[c]);
    float ssum = 0.0f;
    #pragma unroll
    for (int c = 0; c < 10; ++c) ssum += expf(logits[c] - m);
    float lse = logf(ssum);
    if (l < 10) out[b * 10 + l] = logits[l] - m - lse;
}

// ---------------------------------------------------------------------------
extern "C" void kernel_launch(void* const* d_in, const int* in_sizes, int n_in,
                              void* d_out, int out_size, void* d_ws, size_t ws_size,
                              hipStream_t stream) {
    const float* x    = (const float*)d_in[0];
    const float* pos0 = (const float*)d_in[1];
    const int*   ei   = (const int*)d_in[2];
    const float* W1 = (const float*)d_in[4];  const float* b1 = (const float*)d_in[5];
    const float* W2 = (const float*)d_in[6];  const float* b2 = (const float*)d_in[7];
    const float* W3 = (const float*)d_in[8];  const float* b3 = (const float*)d_in[9];
    const float* W4 = (const float*)d_in[10]; const float* b4 = (const float*)d_in[11];
    const float* W5 = (const float*)d_in[12]; const float* b5 = (const float*)d_in[13];
    const float* Wl1 = (const float*)d_in[14]; const float* bl1 = (const float*)d_in[15];
    const float* Wl2 = (const float*)d_in[16]; const float* bl2 = (const float*)d_in[17];
    const int* src0 = ei;
    const int* dst0 = ei + NE;
    float* out = (float*)d_out;

    float* w = (float*)d_ws;
    size_t off = 0;
    auto alloc = [&](size_t n) { float* p = w + off; off += (n + 3) & ~(size_t)3; return p; };

    // --- zero-init region (one memset) ---
    int*      gcnt  = (int*)alloc(32);
    unsigned* bitsG = (unsigned*)alloc(B_GRAPHS * 2048);
    float* hp1   = alloc((size_t)N1 * 16);
    float* psum1 = alloc((size_t)N1 * 3);
    int*   icnt1 = (int*)alloc(N1);
    float* hp2   = alloc((size_t)N2 * 32);
    float* psum2 = alloc((size_t)N2 * 3);
    int*   icnt2 = (int*)alloc(N2);
    float* g     = alloc((size_t)B_GRAPHS * 4096);
    float* hid   = alloc((size_t)B_GRAPHS * 1024);
    size_t zero_bytes = off * sizeof(float);
    // --- abuf (a at every level) ---
    float* abuf = alloc((size_t)N_NODES * 16);
    // --- union 1: binned (dead after bitC) -> h2, h4 ---
    float* ubase = alloc((size_t)NE);
    int*   binned = (int*)ubase;
    float* h2 = ubase;
    float* h4 = h2 + (size_t)N1 * 32;
    // --- union 2: sortedA (dead after gatherA) -> csrC (written by emitC) ---
    int* sortedA = (int*)alloc(NE);
    int* csrC = sortedA;
    // --- rest ---
    int* csrB = (int*)alloc(NE);
    int* H   = (int*)alloc((size_t)B_GRAPHS * 1024 * CPG + 4);
    int* S_A = (int*)alloc((size_t)B_GRAPHS * 512 * CPG + 4);
    int* S_B = (int*)alloc((size_t)B_GRAPHS * 1024 * CPG + 4);
    int* pc  = (int*)alloc(N2);
    int* SC  = (int*)alloc(N2 + 4);
    float* pos1 = alloc((size_t)N1 * 3);
    float* pos2 = alloc((size_t)N2 * 3);
    int* cell = (int*)alloc(N2);
    int* c1   = (int*)alloc(N_NODES);
    int* c2   = (int*)alloc(N1);
    int* c12  = (int*)alloc(N_NODES);
    int* gbase = (int*)alloc(64);
    int* gcur  = (int*)alloc(64);
    int* blocksums = (int*)alloc(2560);
    int* blockpref = (int*)alloc(2560);
    (void)ws_size; (void)in_sizes; (void)n_in; (void)out_size;

    hipMemsetAsync(d_ws, 0, zero_bytes, stream);

    auto hscan = [&](const int* cnts, int* offs, int n) {
        scan_reduce_kernel<<<n / 1024, 256, 0, stream>>>(cnts, blocksums);
        scan_blocks_kernel<<<1, 256, 0, stream>>>(blocksums, blockpref, offs, n / 1024, n);
        scan_write_kernel<<<n / 1024, 256, 0, stream>>>(cnts, blockpref, offs, nullptr);
    };

    // ===== level A: bucket by graph, bucket-16 sort, fused conv1+pool1 =====
    node_a_kernel<1, 16><<<N_NODES / 256, 256, 0, stream>>>(x, pos0, W1, b1, abuf, N_NODES);
    precount_kernel<<<256, 256, 0, stream>>>(dst0, gcnt);
    gscan_kernel<<<1, 64, 0, stream>>>(gcnt, gbase, gcur);
    bucket_kernel<<<NE / 2048, 256, 0, stream>>>(src0, dst0, gcur, binned);
    sort_hist_kernel<512, 0><<<B_GRAPHS * CPG, 1024, 0, stream>>>(binned, gbase, gcur, nullptr, H);
    hscan(H, S_A, B_GRAPHS * 512 * CPG);
    sort_fill_kernel<512, 0><<<B_GRAPHS * CPG, 1024, 0, stream>>>(binned, gbase, gcur, nullptr, S_A, sortedA);
    cluster_kernel<<<N_NODES / 256, 256, 0, stream>>>(pos0, c1, psum1, icnt1, N_NODES, 13, 0.25f, 32);
    gatherA_kernel<<<B_GRAPHS * 512, 512, 0, stream>>>(abuf, pos0, W1 + 16, S_A, sortedA, c1, hp1);
    posfin_kernel<<<N1 / 256, 256, 0, stream>>>(psum1, icnt1, pos1, N1);

    // ===== cluster maps =====
    cluster_kernel<<<N1 / 256, 256, 0, stream>>>(pos1, c2, psum2, icnt2, N1, 10, 0.125f, 16);
    posfin_kernel<<<N2 / 256, 256, 0, stream>>>(psum2, icnt2, pos2, N2);
    c12map_kernel<<<N_NODES / 256, 256, 0, stream>>>(c1, c2, c12);

    // ===== level-B CSR (1024-bin counting sort) =====
    sort_hist_kernel<1024, 1><<<B_GRAPHS * CPG, 1024, 0, stream>>>(binned, gbase, gcur, c1, H);
    hscan(H, S_B, B_GRAPHS * 1024 * CPG);
    sort_fill_kernel<1024, 1><<<B_GRAPHS * CPG, 1024, 0, stream>>>(binned, gbase, gcur, c1, S_B, csrB);

    // ===== level-C CSR (parallel bitmap dedupe; csrC aliases dead sortedA) =====
    bitC_kernel<<<B_GRAPHS * CPG, 1024, 0, stream>>>(binned, gbase, gcur, c12, bitsG);
    popcC_kernel<<<N2 / 256, 256, 0, stream>>>(bitsG, pc);
    hscan(pc, SC, N2);
    emitC_kernel<<<N2 / 256, 256, 0, stream>>>(bitsG, SC, csrC);

    // ===== level B: conv2 (store), conv3 (fused pool2) =====
    node_a_kernel<16, 32><<<N1 / 256, 256, 0, stream>>>(hp1, pos1, W2, b2, abuf, N1);
    gatherR_kernel<32, 0, CPG, 8><<<N1 / 8, 512, 0, stream>>>(abuf, pos1, W2 + 512, S_B, csrB, nullptr, h2, N1 / 8);
    node_a_kernel<32, 32><<<N1 / 256, 256, 0, stream>>>(h2, pos1, W3, b3, abuf, N1);
    gatherR_kernel<32, 1, CPG, 8><<<N1 / 8, 512, 0, stream>>>(abuf, pos1, W3 + 1024, S_B, csrB, c2, hp2, N1 / 8);

    // ===== level C: conv4 (store), conv5 (fused pool_out) =====
    node_a_kernel<32, 64><<<N2 / 256, 256, 0, stream>>>(hp2, pos2, W4, b4, abuf, N2);
    gatherR_kernel<64, 0, 1, 16><<<N2 / 8, 512, 0, stream>>>(abuf, pos2, W4 + 2048, SC, csrC, nullptr, h4, N2 / 8);
    node_a_kernel<64, 64><<<N2 / 256, 256, 0, stream>>>(h4, pos2, W5, b5, abuf, N2);
    cellout_kernel<<<N2 / 256, 256, 0, stream>>>(pos2, cell, N2);
    gatherR_kernel<64, 1, 1, 16><<<N2 / 8, 512, 0, stream>>>(abuf, pos2, W5 + 4096, SC, csrC, cell, g, N2 / 8);

    // ===== MLP head =====
    mlp1_kernel<<<dim3(64, 4), 256, 0, stream>>>(g, Wl1, hid);
    mlp2_kernel<<<32, 64, 0, stream>>>(hid, bl1, Wl2, bl2, out);
}

// Round 14
// 450.346 us; speedup vs baseline: 1.2104x; 1.0312x over previous
//
#include <hip/hip_runtime.h>
#include <cstdint>
#include <cstddef>

#define B_GRAPHS 32
#define NPG      8192
#define N_NODES  (B_GRAPHS * NPG)   // 262144
#define DEG      8
#define NE       (N_NODES * DEG)    // 2097152
#define N1       32768              // B * 32*32  (grid 4)
#define N2       8192               // B * 16*16  (grid 8)
#define BKT_CAP  80
#define CPG      8                  // chunks per graph for parallel sorts

// ---------------------------------------------------------------------------
// Node-level precompute: a[i,o] = b[o] + sum_k h[i,k]*W[k,o] + px*W[IN,o] + py*W[IN+1,o]
// ---------------------------------------------------------------------------
template<int IN, int OUT>
__global__ __launch_bounds__(256)
void node_a_kernel(const float* __restrict__ h, const float* __restrict__ pos,
                   const float* __restrict__ W, const float* __restrict__ bias,
                   float* __restrict__ a, int n) {
    constexpr int FEAT = IN + 2;
    __shared__ float Ws[FEAT * OUT + OUT];
    for (int i = threadIdx.x; i < FEAT * OUT; i += 256) Ws[i] = W[i];
    for (int i = threadIdx.x; i < OUT; i += 256) Ws[FEAT * OUT + i] = bias[i];
    __syncthreads();
    int i = blockIdx.x * 256 + threadIdx.x;
    if (i >= n) return;

    float acc[OUT];
    #pragma unroll
    for (int o = 0; o < OUT; ++o) acc[o] = Ws[FEAT * OUT + o];

    float px = pos[i * 3 + 0], py = pos[i * 3 + 1];
    #pragma unroll
    for (int o = 0; o < OUT; ++o)
        acc[o] += px * Ws[IN * OUT + o] + py * Ws[(IN + 1) * OUT + o];

    if constexpr (IN % 4 == 0) {
        const float4* h4 = (const float4*)(h + (size_t)i * IN);
        for (int k4 = 0; k4 < IN / 4; ++k4) {
            float4 f = h4[k4];
            #pragma unroll
            for (int o = 0; o < OUT; ++o) {
                acc[o] += f.x * Ws[(k4 * 4 + 0) * OUT + o];
                acc[o] += f.y * Ws[(k4 * 4 + 1) * OUT + o];
                acc[o] += f.z * Ws[(k4 * 4 + 2) * OUT + o];
                acc[o] += f.w * Ws[(k4 * 4 + 3) * OUT + o];
            }
        }
    } else {
        for (int k = 0; k < IN; ++k) {
            float f = h[(size_t)i * IN + k];
            #pragma unroll
            for (int o = 0; o < OUT; ++o) acc[o] += f * Ws[k * OUT + o];
        }
    }
    float* ap = a + (size_t)i * OUT;
    #pragma unroll
    for (int o = 0; o < OUT; ++o) ap[o] = acc[o];
}

// ---------------------------------------------------------------------------
// Per-graph edge histogram (gcnt zeroed) + tiny serial scan.
// ---------------------------------------------------------------------------
__global__ __launch_bounds__(256)
void precount_kernel(const int* __restrict__ dst, int* __restrict__ gcnt) {
    __shared__ int hist[B_GRAPHS];
    if (threadIdx.x < B_GRAPHS) hist[threadIdx.x] = 0;
    __syncthreads();
    int gid = blockIdx.x * 256 + threadIdx.x;
    for (int e = gid; e < NE; e += 256 * 256)
        atomicAdd(&hist[dst[e] >> 13], 1);
    __syncthreads();
    if (threadIdx.x < B_GRAPHS) atomicAdd(&gcnt[threadIdx.x], hist[threadIdx.x]);
}

__global__ void gscan_kernel(const int* __restrict__ gcnt, int* __restrict__ gbase,
                             int* __restrict__ gcur) {
    if (threadIdx.x == 0) {
        int run = 0;
        for (int g = 0; g < B_GRAPHS; ++g) {
            gbase[g] = run; gcur[g] = run;
            run += gcnt[g];
        }
        gbase[B_GRAPHS] = run;
    }
}

// ---------------------------------------------------------------------------
// Bucket edges by graph, packed local (src<<13 | dst). Coalesced flushes.
// ---------------------------------------------------------------------------
__global__ __launch_bounds__(256)
void bucket_kernel(const int* __restrict__ src, const int* __restrict__ dst,
                   int* __restrict__ gcur, int* __restrict__ binned) {
    __shared__ int bins[B_GRAPHS][BKT_CAP];
    __shared__ int bcnt[B_GRAPHS], sbase[B_GRAPHS], sn[B_GRAPHS];
    int tid = threadIdx.x;
    if (tid < B_GRAPHS) bcnt[tid] = 0;
    __syncthreads();
    int wgbase = blockIdx.x * 2048;
    for (int sub = 0; sub < 2; ++sub) {
        int e0 = wgbase + sub * 1024 + tid * 4;
        int4 s4 = *(const int4*)&src[e0];
        int4 d4 = *(const int4*)&dst[e0];
        int ss[4] = {s4.x, s4.y, s4.z, s4.w};
        int dd[4] = {d4.x, d4.y, d4.z, d4.w};
        #pragma unroll
        for (int k = 0; k < 4; ++k) {
            int b = dd[k] >> 13;
            int pk = ((ss[k] & 8191) << 13) | (dd[k] & 8191);
            int pos = atomicAdd(&bcnt[b], 1);
            if (pos < BKT_CAP) bins[b][pos] = pk;
            else { int gp = atomicAdd(&gcur[b], 1); binned[gp] = pk; }
        }
        __syncthreads();
        if (tid < B_GRAPHS) {
            int nb = min(bcnt[tid], BKT_CAP);
            sn[tid] = nb;
            sbase[tid] = atomicAdd(&gcur[tid], nb);
        }
        __syncthreads();
        int b = tid >> 3, r = tid & 7;
        for (int k = r; k < sn[b]; k += 8) binned[sbase[b] + k] = bins[b][k];
        __syncthreads();
        if (tid < B_GRAPHS) bcnt[tid] = 0;
        __syncthreads();
    }
}

// ---------------------------------------------------------------------------
// Parallel chunked counting sort (hist -> global scan -> fill), 8 chunks/graph.
// ---------------------------------------------------------------------------
template<int BINS, int LEVB>
__global__ __launch_bounds__(1024)
void sort_hist_kernel(const int* __restrict__ binned, const int* __restrict__ gbase,
                      const int* __restrict__ gend, const int* __restrict__ c1,
                      int* __restrict__ H) {
    __shared__ int hist[BINS];
    int wg = blockIdx.x, g = wg >> 3, sub = wg & 7, t = threadIdx.x;
    for (int i = t; i < BINS; i += 1024) hist[i] = 0;
    __syncthreads();
    int segb = gbase[g], sege = gend[g];
    int csz = (sege - segb + CPG - 1) / CPG;
    int e0 = segb + sub * csz, e1 = min(e0 + csz, sege);
    int nodeb = g * NPG;
    for (int e = e0 + t; e < e1; e += 1024) {
        int pk = binned[e];
        if (LEVB) {
            int sc = c1[nodeb + (pk >> 13)];
            int dc = c1[nodeb + (pk & 8191)];
            if (sc != dc) atomicAdd(&hist[dc & (BINS - 1)], 1);
        } else {
            atomicAdd(&hist[(pk & 8191) >> 4], 1);
        }
    }
    __syncthreads();
    for (int b = t; b < BINS; b += 1024)
        H[(size_t)(g * BINS + b) * CPG + sub] = hist[b];
}

template<int BINS, int LEVB>
__global__ __launch_bounds__(1024)
void sort_fill_kernel(const int* __restrict__ binned, const int* __restrict__ gbase,
                      const int* __restrict__ gend, const int* __restrict__ c1,
                      const int* __restrict__ S, int* __restrict__ outv) {
    __shared__ int cur[BINS];
    int wg = blockIdx.x, g = wg >> 3, sub = wg & 7, t = threadIdx.x;
    for (int b = t; b < BINS; b += 1024)
        cur[b] = S[(size_t)(g * BINS + b) * CPG + sub];
    __syncthreads();
    int segb = gbase[g], sege = gend[g];
    int csz = (sege - segb + CPG - 1) / CPG;
    int e0 = segb + sub * csz, e1 = min(e0 + csz, sege);
    int nodeb = g * NPG;
    for (int e = e0 + t; e < e1; e += 1024) {
        int pk = binned[e];
        if (LEVB) {
            int sc = c1[nodeb + (pk >> 13)];
            int dc = c1[nodeb + (pk & 8191)];
            if (sc != dc) {
                int p = atomicAdd(&cur[dc & (BINS - 1)], 1);
                outv[p] = sc;
            }
        } else {
            int p = atomicAdd(&cur[(pk & 8191) >> 4], 1);
            outv[p] = pk;
        }
    }
}

// ---------------------------------------------------------------------------
// Hierarchical exclusive scan (n % 1024 == 0, nb up to ~2048).
// ---------------------------------------------------------------------------
__global__ __launch_bounds__(256)
void scan_reduce_kernel(const int* __restrict__ counts, int* __restrict__ blocksums) {
    int t = threadIdx.x;
    int4 v = *(const int4*)&counts[blockIdx.x * 1024 + t * 4];
    int s = v.x + v.y + v.z + v.w;
    #pragma unroll
    for (int off = 32; off > 0; off >>= 1) s += __shfl_xor(s, off, 64);
    __shared__ int ws[4];
    if ((t & 63) == 0) ws[t >> 6] = s;
    __syncthreads();
    if (t == 0) blocksums[blockIdx.x] = ws[0] + ws[1] + ws[2] + ws[3];
}

__global__ __launch_bounds__(256)
void scan_blocks_kernel(const int* __restrict__ blocksums, int* __restrict__ blockpref,
                        int* __restrict__ offsets, int nb, int n) {
    __shared__ int sh[256];
    int t = threadIdx.x;
    int C = (nb + 255) / 256;
    int base = t * C;
    int s = 0;
    for (int i = 0; i < C; ++i) { int idx = base + i; if (idx < nb) s += blocksums[idx]; }
    sh[t] = s;
    __syncthreads();
    #pragma unroll
    for (int d = 1; d < 256; d <<= 1) {
        int u = (t >= d) ? sh[t - d] : 0;
        __syncthreads();
        sh[t] += u;
        __syncthreads();
    }
    int run = sh[t] - s;
    for (int i = 0; i < C; ++i) {
        int idx = base + i;
        if (idx < nb) { int v = blocksums[idx]; blockpref[idx] = run; run += v; }
    }
    if (t == 255) offsets[n] = sh[255];
}

__global__ __launch_bounds__(256)
void scan_write_kernel(const int* __restrict__ counts, const int* __restrict__ blockpref,
                       int* __restrict__ offsets, int* __restrict__ cursor) {
    int b = blockIdx.x, t = threadIdx.x;
    int base = b * 1024 + t * 4;
    int4 v = *(const int4*)&counts[base];
    int s = v.x + v.y + v.z + v.w;
    __shared__ int sh[256];
    sh[t] = s;
    __syncthreads();
    #pragma unroll
    for (int d = 1; d < 256; d <<= 1) {
        int u = (t >= d) ? sh[t - d] : 0;
        __syncthreads();
        sh[t] += u;
        __syncthreads();
    }
    int pref = blockpref[b] + sh[t] - s;
    int4 o;
    o.x = pref;
    o.y = pref + v.x;
    o.z = o.y + v.y;
    o.w = o.z + v.z;
    *(int4*)&offsets[base] = o;
    if (cursor) *(int4*)&cursor[base] = o;
}

// ---------------------------------------------------------------------------
// Fused voxel cluster + pos-mean: ONE workgroup per graph owns all its
// clusters exclusively -> accumulate in LDS, write pos_new with PLAIN stores
// (zero global atomics; round-13's scattered-atomic version wrote 31 MB).
// Also fuses posfin. CELLS in {32,16}; NODES_PG in {8192,1024}.
// ---------------------------------------------------------------------------
template<int CELLS, int NODES_PG>
__global__ __launch_bounds__(1024)
void clusterpos_kernel(const float* __restrict__ pos, int* __restrict__ cluster,
                       float* __restrict__ pos_new) {
    constexpr int NC = CELLS * CELLS;
    __shared__ float sx[NC], sy[NC], sz[NC];
    __shared__ int scnt[NC];
    int g = blockIdx.x, t = threadIdx.x;
    for (int i = t; i < NC; i += 1024) { sx[i] = 0; sy[i] = 0; sz[i] = 0; scnt[i] = 0; }
    __syncthreads();
    int nodeb = g * NODES_PG;
    constexpr float INVG = (float)CELLS / 128.0f;
    #pragma unroll
    for (int k = 0; k < NODES_PG / 1024; ++k) {
        int i = nodeb + k * 1024 + t;
        float px = pos[i * 3 + 0], py = pos[i * 3 + 1], pz = pos[i * 3 + 2];
        int ix = min(max((int)floorf(px * INVG), 0), CELLS - 1);
        int iy = min(max((int)floorf(py * INVG), 0), CELLS - 1);
        int c = iy * CELLS + ix;
        cluster[i] = g * NC + c;
        atomicAdd(&sx[c], px);
        atomicAdd(&sy[c], py);
        atomicAdd(&sz[c], pz);
        atomicAdd(&scnt[c], 1);
    }
    __syncthreads();
    for (int i = t; i < NC; i += 1024) {
        float cc = fmaxf((float)scnt[i], 1.0f);
        int o = g * NC + i;
        pos_new[o * 3 + 0] = sx[i] / cc;
        pos_new[o * 3 + 1] = sy[i] / cc;
        pos_new[o * 3 + 2] = sz[i] / cc;
    }
}

// ---------------------------------------------------------------------------
// Level-A fused conv1+pool1: one wg per 16-dst bucket; per-(dst,ch) LDS
// atomicMax slots, 32 edge streams x 16 ch, x4 batched prefetch.
// ---------------------------------------------------------------------------
__global__ __launch_bounds__(512)
void gatherA_kernel(const float* __restrict__ a, const float* __restrict__ pos,
                    const float* __restrict__ Wp, const int* __restrict__ S,
                    const int* __restrict__ sortedA, const int* __restrict__ c1,
                    float* __restrict__ hp1) {
    __shared__ unsigned slot[256];
    int bid = blockIdx.x;
    int v = (bid & 7) * (B_GRAPHS * 512 / 8) + (bid >> 3);   // XCD-contiguous graphs
    int g = v >> 9;
    int t = threadIdx.x;
    if (t < 256) slot[t] = 0u;
    __syncthreads();
    int start = S[(size_t)v * CPG], end = S[(size_t)(v + 1) * CPG];
    int nodeb = g * NPG;
    int ch = t & 15, el = t >> 4;        // 32 edge streams
    for (int j = start + el; j < end; j += 128) {
        int pk[4];
        float vv[4];
        #pragma unroll
        for (int u = 0; u < 4; ++u) {
            int jj = j + u * 32;
            pk[u] = sortedA[jj < end ? jj : end - 1];
        }
        #pragma unroll
        for (int u = 0; u < 4; ++u)
            vv[u] = a[(size_t)(nodeb + (pk[u] >> 13)) * 16 + ch];
        #pragma unroll
        for (int u = 0; u < 4; ++u) {
            unsigned uu = __float_as_uint(vv[u]);
            unsigned key = (uu & 0x80000000u) ? ~uu : (uu | 0x80000000u);
            atomicMax(&slot[((pk[u] & 15) << 4) + ch], key);
        }
    }
    __syncthreads();
    if (t < 256) {
        int dl = t >> 4;
        unsigned k = slot[(dl << 4) + ch];
        if (k) {
            unsigned u = (k & 0x80000000u) ? (k ^ 0x80000000u) : ~k;
            float m = __uint_as_float(u);
            int dst = nodeb + ((v & 511) << 4) + dl;
            float px = pos[dst * 3 + 0], py = pos[dst * 3 + 1];
            float val = fmaxf(m - (px * Wp[ch] + py * Wp[16 + ch]), 0.0f);
            if (val > 0.0f)
                atomicMax((int*)&hp1[(size_t)c1[dst] * 16 + ch], __float_as_int(val));
        }
    }
}

// ---------------------------------------------------------------------------
// Level-C dedupe bitmap (parallel): LDS bitmap per chunk, merge via atomicOr.
// ---------------------------------------------------------------------------
__global__ __launch_bounds__(1024)
void bitC_kernel(const int* __restrict__ binned, const int* __restrict__ gbase,
                 const int* __restrict__ gend, const int* __restrict__ c12,
                 unsigned* __restrict__ bitsG) {
    __shared__ unsigned bits[2048];
    int wg = blockIdx.x, g = wg >> 3, sub = wg & 7, t = threadIdx.x;
    for (int i = t; i < 2048; i += 1024) bits[i] = 0;
    __syncthreads();
    int segb = gbase[g], sege = gend[g];
    int csz = (sege - segb + CPG - 1) / CPG;
    int e0 = segb + sub * csz, e1 = min(e0 + csz, sege);
    int nodeb = g * NPG, clb = g * 256;
    for (int e = e0 + t; e < e1; e += 1024) {
        int pk = binned[e];
        int sc = c12[nodeb + (pk >> 13)] - clb;
        int dc = c12[nodeb + (pk & 8191)] - clb;
        if (sc != dc) atomicOr(&bits[(dc << 3) + (sc >> 5)], 1u << (sc & 31));
    }
    __syncthreads();
    for (int i = t; i < 2048; i += 1024) {
        unsigned wv = bits[i];
        if (wv) atomicOr(&bitsG[((size_t)g << 11) + i], wv);
    }
}

__global__ __launch_bounds__(256)
void popcC_kernel(const unsigned* __restrict__ bitsG, int* __restrict__ pc) {
    int i = blockIdx.x * 256 + threadIdx.x;
    int s = 0;
    #pragma unroll
    for (int k = 0; k < 8; ++k) s += __popc(bitsG[((size_t)i << 3) + k]);
    pc[i] = s;
}

__global__ __launch_bounds__(256)
void emitC_kernel(const unsigned* __restrict__ bitsG, const int* __restrict__ SC,
                  int* __restrict__ csrC) {
    int i = blockIdx.x * 256 + threadIdx.x;
    int clb = (i >> 8) << 8;
    int p = SC[i];
    #pragma unroll
    for (int w = 0; w < 8; ++w) {
        unsigned word = bitsG[((size_t)i << 3) + w];
        while (word) {
            int b = __ffs(word) - 1;
            word &= word - 1;
            csrC[p++] = clb + (w << 5) + b;
        }
    }
}

// ---------------------------------------------------------------------------
// Coarse gather-max conv (wave per node, FPL floats/lane, XCD-swizzled),
// inner loop unrolled x2 (duplicate-edge trick, max idempotent).
// MODE 0: float4 stores. MODE 1: wave-local LDS transpose -> coalesced atomics.
// ---------------------------------------------------------------------------
template<int OUT, int MODE, int STRIDE, int FPL>
__global__ __launch_bounds__(512)
void gatherR_kernel(const float* __restrict__ a, const float* __restrict__ pos,
                    const float* __restrict__ Wp, const int* __restrict__ S,
                    const int* __restrict__ csr, const int* __restrict__ outmap,
                    float* __restrict__ out, int nblocks) {
    constexpr int CH = OUT / FPL;
    constexpr int ES = 64 / CH;
    constexpr int NV = FPL / 4;
    int bid = blockIdx.x;
    int sb = (bid & 7) * (nblocks >> 3) + (bid >> 3);
    int v = sb * 8 + (threadIdx.x >> 6);
    int lane = threadIdx.x & 63;
    int ch = lane % CH, s = lane / CH;
    int l = S[(size_t)v * STRIDE], h = S[(size_t)(v + 1) * STRIDE];
    float4 m[NV];
    #pragma unroll
    for (int q = 0; q < NV; ++q) m[q] = make_float4(-1e30f, -1e30f, -1e30f, -1e30f);
    for (int j = l + s; j < h; j += 2 * ES) {
        int j1 = j + ES;
        int sc0 = csr[j];
        int sc1 = csr[j1 < h ? j1 : j];
        const float4* ap0 = (const float4*)&a[(size_t)sc0 * OUT + ch * FPL];
        const float4* ap1 = (const float4*)&a[(size_t)sc1 * OUT + ch * FPL];
        #pragma unroll
        for (int q = 0; q < NV; ++q) {
            float4 f0 = ap0[q];
            float4 f1 = ap1[q];
            m[q].x = fmaxf(m[q].x, fmaxf(f0.x, f1.x));
            m[q].y = fmaxf(m[q].y, fmaxf(f0.y, f1.y));
            m[q].z = fmaxf(m[q].z, fmaxf(f0.z, f1.z));
            m[q].w = fmaxf(m[q].w, fmaxf(f0.w, f1.w));
        }
    }
    #pragma unroll
    for (int st = CH; st < 64; st <<= 1) {
        #pragma unroll
        for (int q = 0; q < NV; ++q) {
            m[q].x = fmaxf(m[q].x, __shfl_xor(m[q].x, st, 64));
            m[q].y = fmaxf(m[q].y, __shfl_xor(m[q].y, st, 64));
            m[q].z = fmaxf(m[q].z, __shfl_xor(m[q].z, st, 64));
            m[q].w = fmaxf(m[q].w, __shfl_xor(m[q].w, st, 64));
        }
    }
    if (MODE == 0) {
        if (s == 0) {
            float px = pos[v * 3 + 0], py = pos[v * 3 + 1];
            bool ne = h > l;
            #pragma unroll
            for (int q = 0; q < NV; ++q) {
                float4 wx = *(const float4*)&Wp[ch * FPL + q * 4];
                float4 wy = *(const float4*)&Wp[OUT + ch * FPL + q * 4];
                float4 val;
                val.x = ne ? fmaxf(m[q].x - (px * wx.x + py * wy.x), 0.0f) : 0.0f;
                val.y = ne ? fmaxf(m[q].y - (px * wx.y + py * wy.y), 0.0f) : 0.0f;
                val.z = ne ? fmaxf(m[q].z - (px * wx.z + py * wy.z), 0.0f) : 0.0f;
                val.w = ne ? fmaxf(m[q].w - (px * wx.w + py * wy.w), 0.0f) : 0.0f;
                *(float4*)&out[(size_t)v * OUT + ch * FPL + q * 4] = val;
            }
        }
    } else {
        __shared__ float red[8][OUT];
        int wid = threadIdx.x >> 6;
        if (s == 0) {
            #pragma unroll
            for (int q = 0; q < NV; ++q)
                *(float4*)&red[wid][ch * FPL + q * 4] = m[q];
        }
        if (lane < OUT) {
            float px = pos[v * 3 + 0], py = pos[v * 3 + 1];
            float val = red[wid][lane];
            float ct = px * Wp[lane] + py * Wp[OUT + lane];
            val = (h > l) ? fmaxf(val - ct, 0.0f) : 0.0f;
            if (val > 0.0f)
                atomicMax((int*)&out[(size_t)outmap[v] * OUT + lane], __float_as_int(val));
        }
    }
}

// ---------------------------------------------------------------------------
// out-cells; c12 compose.
// ---------------------------------------------------------------------------
__global__ __launch_bounds__(256)
void cellout_kernel(const float* __restrict__ pos, int* __restrict__ cell, int n) {
    int i = blockIdx.x * 256 + threadIdx.x;
    if (i >= n) return;
    float px = pos[i * 3 + 0], py = pos[i * 3 + 1];
    int ix = min(max((int)floorf(px * (1.0f / 16.0f)), 0), 7);
    int iy = min(max((int)floorf(py * (1.0f / 16.0f)), 0), 7);
    cell[i] = (i >> 8) * 64 + iy * 8 + ix;
}

__global__ __launch_bounds__(256)
void c12map_kernel(const int* __restrict__ c1, const int* __restrict__ c2,
                   int* __restrict__ c12) {
    int i = blockIdx.x * 256 + threadIdx.x;
    if (i < N_NODES) c12[i] = c2[c1[i]];
}

// ---------------------------------------------------------------------------
// MLP head. mlp1 v3: grid (64 k-slabs x 4 col-tiles) = 256 blocks (1/CU).
// ---------------------------------------------------------------------------
__global__ __launch_bounds__(256)
void mlp1_kernel(const float* __restrict__ g, const float* __restrict__ Wl1,
                 float* __restrict__ hid) {
    __shared__ float gs[64][32];
    int kc = blockIdx.x, oc = blockIdx.y, t = threadIdx.x;
    int kbase = kc * 64;
    for (int i = t; i < 2048; i += 256) {
        int j = i >> 5, b = i & 31;
        gs[j][b] = g[b * 4096 + kbase + j];
    }
    __syncthreads();
    int col = oc * 256 + t;
    float acc[32];
    #pragma unroll
    for (int b = 0; b < 32; ++b) acc[b] = 0.0f;
    for (int j = 0; j < 64; ++j) {
        float wv = Wl1[(size_t)(kbase + j) * 1024 + col];
        const float4* gv = (const float4*)&gs[j][0];
        #pragma unroll
        for (int b4 = 0; b4 < 8; ++b4) {
            float4 f = gv[b4];
            acc[b4 * 4 + 0] += f.x * wv;
            acc[b4 * 4 + 1] += f.y * wv;
            acc[b4 * 4 + 2] += f.z * wv;
            acc[b4 * 4 + 3] += f.w * wv;
        }
    }
    #pragma unroll
    for (int b = 0; b < 32; ++b)
        atomicAdd(&hid[b * 1024 + col], acc[b]);
}

__global__ __launch_bounds__(64)
void mlp2_kernel(const float* __restrict__ hid, const float* __restrict__ bl1,
                 const float* __restrict__ Wl2, const float* __restrict__ bl2,
                 float* __restrict__ out) {
    int b = blockIdx.x, l = threadIdx.x;
    float hv[16];
    #pragma unroll
    for (int i = 0; i < 16; ++i) {
        int idx = l + i * 64;
        hv[i] = fmaxf(hid[(size_t)b * 1024 + idx] + bl1[idx], 0.0f);
    }
    float logits[10];
    #pragma unroll
    for (int c = 0; c < 10; ++c) {
        float p = 0.0f;
        #pragma unroll
        for (int i = 0; i < 16; ++i)
            p += hv[i] * Wl2[(size_t)(l + i * 64) * 10 + c];
        #pragma unroll
        for (int off = 32; off > 0; off >>= 1) p += __shfl_xor(p, off, 64);
        logits[c] = p + bl2[c];
    }
    float m = logits[0];
    #pragma unroll
    for (int c = 1; c < 10; ++c) m = fmaxf(m, logits[c]);
    float ssum = 0.0f;
    #pragma unroll
    for (int c = 0; c < 10; ++c) ssum += expf(logits[c] - m);
    float lse = logf(ssum);
    if (l < 10) out[b * 10 + l] = logits[l] - m - lse;
}

// ---------------------------------------------------------------------------
extern "C" void kernel_launch(void* const* d_in, const int* in_sizes, int n_in,
                              void* d_out, int out_size, void* d_ws, size_t ws_size,
                              hipStream_t stream) {
    const float* x    = (const float*)d_in[0];
    const float* pos0 = (const float*)d_in[1];
    const int*   ei   = (const int*)d_in[2];
    const float* W1 = (const float*)d_in[4];  const float* b1 = (const float*)d_in[5];
    const float* W2 = (const float*)d_in[6];  const float* b2 = (const float*)d_in[7];
    const float* W3 = (const float*)d_in[8];  const float* b3 = (const float*)d_in[9];
    const float* W4 = (const float*)d_in[10]; const float* b4 = (const float*)d_in[11];
    const float* W5 = (const float*)d_in[12]; const float* b5 = (const float*)d_in[13];
    const float* Wl1 = (const float*)d_in[14]; const float* bl1 = (const float*)d_in[15];
    const float* Wl2 = (const float*)d_in[16]; const float* bl2 = (const float*)d_in[17];
    const int* src0 = ei;
    const int* dst0 = ei + NE;
    float* out = (float*)d_out;

    float* w = (float*)d_ws;
    size_t off = 0;
    auto alloc = [&](size_t n) { float* p = w + off; off += (n + 3) & ~(size_t)3; return p; };

    // --- zero-init region (one memset) ---
    int*      gcnt  = (int*)alloc(32);
    unsigned* bitsG = (unsigned*)alloc(B_GRAPHS * 2048);
    float* hp1   = alloc((size_t)N1 * 16);
    float* hp2   = alloc((size_t)N2 * 32);
    float* g     = alloc((size_t)B_GRAPHS * 4096);
    float* hid   = alloc((size_t)B_GRAPHS * 1024);
    size_t zero_bytes = off * sizeof(float);
    // --- abuf (a at every level) ---
    float* abuf = alloc((size_t)N_NODES * 16);
    // --- union 1: binned (dead after bitC) -> h2, h4 ---
    float* ubase = alloc((size_t)NE);
    int*   binned = (int*)ubase;
    float* h2 = ubase;
    float* h4 = h2 + (size_t)N1 * 32;
    // --- union 2: sortedA (dead after gatherA) -> csrC (written by emitC) ---
    int* sortedA = (int*)alloc(NE);
    int* csrC = sortedA;
    // --- rest ---
    int* csrB = (int*)alloc(NE);
    int* H   = (int*)alloc((size_t)B_GRAPHS * 1024 * CPG + 4);
    int* S_A = (int*)alloc((size_t)B_GRAPHS * 512 * CPG + 4);
    int* S_B = (int*)alloc((size_t)B_GRAPHS * 1024 * CPG + 4);
    int* pc  = (int*)alloc(N2);
    int* SC  = (int*)alloc(N2 + 4);
    float* pos1 = alloc((size_t)N1 * 3);
    float* pos2 = alloc((size_t)N2 * 3);
    int* cell = (int*)alloc(N2);
    int* c1   = (int*)alloc(N_NODES);
    int* c2   = (int*)alloc(N1);
    int* c12  = (int*)alloc(N_NODES);
    int* gbase = (int*)alloc(64);
    int* gcur  = (int*)alloc(64);
    int* blocksums = (int*)alloc(2560);
    int* blockpref = (int*)alloc(2560);
    (void)ws_size; (void)in_sizes; (void)n_in; (void)out_size;

    hipMemsetAsync(d_ws, 0, zero_bytes, stream);

    auto hscan = [&](const int* cnts, int* offs, int n) {
        scan_reduce_kernel<<<n / 1024, 256, 0, stream>>>(cnts, blocksums);
        scan_blocks_kernel<<<1, 256, 0, stream>>>(blocksums, blockpref, offs, n / 1024, n);
        scan_write_kernel<<<n / 1024, 256, 0, stream>>>(cnts, blockpref, offs, nullptr);
    };

    // ===== level A: bucket by graph, bucket-16 sort, fused conv1+pool1 =====
    node_a_kernel<1, 16><<<N_NODES / 256, 256, 0, stream>>>(x, pos0, W1, b1, abuf, N_NODES);
    precount_kernel<<<256, 256, 0, stream>>>(dst0, gcnt);
    gscan_kernel<<<1, 64, 0, stream>>>(gcnt, gbase, gcur);
    bucket_kernel<<<NE / 2048, 256, 0, stream>>>(src0, dst0, gcur, binned);
    sort_hist_kernel<512, 0><<<B_GRAPHS * CPG, 1024, 0, stream>>>(binned, gbase, gcur, nullptr, H);
    hscan(H, S_A, B_GRAPHS * 512 * CPG);
    sort_fill_kernel<512, 0><<<B_GRAPHS * CPG, 1024, 0, stream>>>(binned, gbase, gcur, nullptr, S_A, sortedA);
    clusterpos_kernel<32, NPG><<<B_GRAPHS, 1024, 0, stream>>>(pos0, c1, pos1);
    gatherA_kernel<<<B_GRAPHS * 512, 512, 0, stream>>>(abuf, pos0, W1 + 16, S_A, sortedA, c1, hp1);

    // ===== cluster maps (fused pool2 cluster + pos mean) =====
    clusterpos_kernel<16, 1024><<<B_GRAPHS, 1024, 0, stream>>>(pos1, c2, pos2);
    c12map_kernel<<<N_NODES / 256, 256, 0, stream>>>(c1, c2, c12);

    // ===== level-B CSR (1024-bin counting sort) =====
    sort_hist_kernel<1024, 1><<<B_GRAPHS * CPG, 1024, 0, stream>>>(binned, gbase, gcur, c1, H);
    hscan(H, S_B, B_GRAPHS * 1024 * CPG);
    sort_fill_kernel<1024, 1><<<B_GRAPHS * CPG, 1024, 0, stream>>>(binned, gbase, gcur, c1, S_B, csrB);

    // ===== level-C CSR (parallel bitmap dedupe; csrC aliases dead sortedA) =====
    bitC_kernel<<<B_GRAPHS * CPG, 1024, 0, stream>>>(binned, gbase, gcur, c12, bitsG);
    popcC_kernel<<<N2 / 256, 256, 0, stream>>>(bitsG, pc);
    hscan(pc, SC, N2);
    emitC_kernel<<<N2 / 256, 256, 0, stream>>>(bitsG, SC, csrC);

    // ===== level B: conv2 (store), conv3 (fused pool2) =====
    node_a_kernel<16, 32><<<N1 / 256, 256, 0, stream>>>(hp1, pos1, W2, b2, abuf, N1);
    gatherR_kernel<32, 0, CPG, 8><<<N1 / 8, 512, 0, stream>>>(abuf, pos1, W2 + 512, S_B, csrB, nullptr, h2, N1 / 8);
    node_a_kernel<32, 32><<<N1 / 256, 256, 0, stream>>>(h2, pos1, W3, b3, abuf, N1);
    gatherR_kernel<32, 1, CPG, 8><<<N1 / 8, 512, 0, stream>>>(abuf, pos1, W3 + 1024, S_B, csrB, c2, hp2, N1 / 8);

    // ===== level C: conv4 (store), conv5 (fused pool_out) =====
    node_a_kernel<32, 64><<<N2 / 256, 256, 0, stream>>>(hp2, pos2, W4, b4, abuf, N2);
    gatherR_kernel<64, 0, 1, 16><<<N2 / 8, 512, 0, stream>>>(abuf, pos2, W4 + 2048, SC, csrC, nullptr, h4, N2 / 8);
    node_a_kernel<64, 64><<<N2 / 256, 256, 0, stream>>>(h4, pos2, W5, b5, abuf, N2);
    cellout_kernel<<<N2 / 256, 256, 0, stream>>>(pos2, cell, N2);
    gatherR_kernel<64, 1, 1, 16><<<N2 / 8, 512, 0, stream>>>(abuf, pos2, W5 + 4096, SC, csrC, cell, g, N2 / 8);

    // ===== MLP head =====
    mlp1_kernel<<<dim3(64, 4), 256, 0, stream>>>(g, Wl1, hid);
    mlp2_kernel<<<32, 64, 0, stream>>>(hid, bl1, Wl2, bl2, out);
}